// Round 12
// baseline (429.560 us; speedup 1.0000x reference)
//
#include <hip/hip_runtime.h>

// GCN on MI355X. R12: fill's atomic scatter (102MB writes, one dirty line per
// edge) replaced by a 2-level counting sort with L2-write-merging:
//   bucket_hist (dst>>6, LDS) -> chunked scan -> bucket_place (per-block LDS
//   cursors => ~16-record contiguous runs, {src,dst} tmp) -> fine_sort (one
//   block per bucket, 64 LDS cursors from off[] => final {src,w} CSR recs).
// Consumers (prop6 / pull-aggregate / MFMA gemms) unchanged from R11.

#define HDIM 128
#define NB1 128  // sort blocks (level-1)

typedef __attribute__((ext_vector_type(8))) short bf16x8;
typedef __attribute__((ext_vector_type(4))) float f32x4;

__device__ inline unsigned short bf16rn(float f) {
  unsigned u = __float_as_uint(f);
  unsigned r = (u + 0x7FFFu + ((u >> 16) & 1u)) >> 16;
  return (unsigned short)r;
}
__device__ inline float bf16tof(unsigned short h) {
  return __uint_as_float(((unsigned)h) << 16);
}

// ---------------- degree / dinv ----------------

__global__ void init_deg(int* deg, int n) {
  int i = blockIdx.x * blockDim.x + threadIdx.x;
  if (i < n) deg[i] = 1;  // self loop
}

__global__ void hist_kernel(const int* __restrict__ ei, int E, int* __restrict__ deg) {
  int e = blockIdx.x * blockDim.x + threadIdx.x;
  if (e < E) atomicAdd(&deg[ei[E + e]], 1);  // dst = ei[1][e]
}

__global__ void dinv_kernel(const int* __restrict__ deg, float* __restrict__ dinv, int n) {
  int i = blockIdx.x * blockDim.x + threadIdx.x;
  if (i < n) dinv[i] = rsqrtf((float)deg[i]);
}

// --- parallel exclusive scan of (deg[i]-1) -> off[] ---

__global__ __launch_bounds__(256) void block_sums_kernel(const int* __restrict__ deg,
                                                         int* __restrict__ bsums, int n) {
  int i = blockIdx.x * 256 + threadIdx.x;
  int v = (i < n) ? (deg[i] - 1) : 0;
#pragma unroll
  for (int d = 1; d < 64; d <<= 1) v += __shfl_xor(v, d, 64);
  __shared__ int ws[4];
  int lane = threadIdx.x & 63, wid = threadIdx.x >> 6;
  if (lane == 0) ws[wid] = v;
  __syncthreads();
  if (threadIdx.x == 0) bsums[blockIdx.x] = ws[0] + ws[1] + ws[2] + ws[3];
}

__global__ __launch_bounds__(256) void scan_bsums_kernel(const int* __restrict__ bsums,
                                                         int* __restrict__ bscan, int nb) {
  int tid = threadIdx.x, lane = tid & 63, wid = tid >> 6;
  int v = (tid < nb) ? bsums[tid] : 0;
  int inc = v;
#pragma unroll
  for (int d = 1; d < 64; d <<= 1) {
    int t = __shfl_up(inc, (unsigned)d, 64);
    if (lane >= d) inc += t;
  }
  __shared__ int ws[4];
  if (lane == 63) ws[wid] = inc;
  __syncthreads();
  int woff = 0;
  for (int w = 0; w < wid; ++w) woff += ws[w];
  inc += woff;
  if (tid < nb) bscan[tid] = inc - v;
}

__global__ __launch_bounds__(256) void write_off_kernel(const int* __restrict__ deg,
                                                        const int* __restrict__ bscan,
                                                        int* __restrict__ off, int n) {
  int i = blockIdx.x * 256 + threadIdx.x;
  int v = (i < n) ? (deg[i] - 1) : 0;
  int lane = threadIdx.x & 63, wid = threadIdx.x >> 6;
  int inc = v;
#pragma unroll
  for (int d = 1; d < 64; d <<= 1) {
    int t = __shfl_up(inc, (unsigned)d, 64);
    if (lane >= d) inc += t;
  }
  __shared__ int ws[4];
  if (lane == 63) ws[wid] = inc;
  __syncthreads();
  int woff = 0;
  for (int w = 0; w < wid; ++w) woff += ws[w];
  inc += woff;
  int base = bscan[blockIdx.x];
  if (i < n) {
    int ex = base + inc - v;
    off[i] = ex;
    if (i == n - 1) off[n] = base + inc;
  }
}

// ---------------- 2-level counting sort ----------------

// level-1 histogram: gh[k*NB1 + b] = #edges of bucket k in block b's chunk
__global__ __launch_bounds__(1024) void bucket_hist(const int* __restrict__ ei, int E,
                                                    int chunk, int* __restrict__ gh, int nbk) {
  __shared__ int h[1024];
  int tid = threadIdx.x, b = blockIdx.x;
  for (int i = tid; i < nbk; i += 1024) h[i] = 0;
  __syncthreads();
  int s = b * chunk, e = min(E, s + chunk);
  for (int i = s + tid; i < e; i += 1024) atomicAdd(&h[ei[E + i] >> 6], 1);
  __syncthreads();
  for (int k = tid; k < nbk; k += 1024) gh[k * NB1 + b] = h[k];
}

// single-block chunked exclusive scan over M ints
__global__ __launch_bounds__(256) void gscan_kernel(const int* __restrict__ in,
                                                    int* __restrict__ outv, int M) {
  __shared__ int wsum[4];
  __shared__ int carry_s;
  int tid = threadIdx.x, lane = tid & 63, wid = tid >> 6;
  if (tid == 0) carry_s = 0;
  __syncthreads();
  int nchunks = (M + 4095) / 4096;
  for (int c = 0; c < nchunks; ++c) {
    int base = c * 4096 + tid * 16;
    int v[16];
#pragma unroll
    for (int j = 0; j < 16; ++j) {
      int i = base + j;
      v[j] = (i < M) ? in[i] : 0;
    }
    int s = 0;
#pragma unroll
    for (int j = 0; j < 16; ++j) { int t = v[j]; v[j] = s; s += t; }
    int tot = s;
    int inc = tot;
#pragma unroll
    for (int d = 1; d < 64; d <<= 1) {
      int t = __shfl_up(inc, (unsigned)d, 64);
      if (lane >= d) inc += t;
    }
    if (lane == 63) wsum[wid] = inc;
    int texcl = inc - tot;
    __syncthreads();
    int wexcl = 0, ctot = 0;
#pragma unroll
    for (int w = 0; w < 4; ++w) {
      int ws = wsum[w];
      if (w < wid) wexcl += ws;
      ctot += ws;
    }
    int cbase = carry_s + wexcl + texcl;
#pragma unroll
    for (int j = 0; j < 16; ++j) {
      int i = base + j;
      if (i < M) outv[i] = cbase + v[j];
    }
    __syncthreads();
    if (tid == 0) carry_s += ctot;
    __syncthreads();
  }
}

// level-1 place: sequential positions per (bucket,block) -> L2 write-merging
__global__ __launch_bounds__(1024) void bucket_place(const int* __restrict__ ei, int E,
                                                     int chunk, const int* __restrict__ ghs,
                                                     int2* __restrict__ tmp, int nbk) {
  __shared__ int cur[1024];
  int tid = threadIdx.x, b = blockIdx.x;
  for (int k = tid; k < nbk; k += 1024) cur[k] = ghs[k * NB1 + b];
  __syncthreads();
  int s = b * chunk, e = min(E, s + chunk);
  for (int i = s + tid; i < e; i += 1024) {
    int src = ei[i], dst = ei[E + i];
    int pos = atomicAdd(&cur[dst >> 6], 1);
    tmp[pos] = make_int2(src, dst);
  }
}

// level-2: one block per bucket; 64 LDS cursors from off[] -> final {src,w}
__global__ __launch_bounds__(256) void fine_sort(const int2* __restrict__ tmp,
                                                 const int* __restrict__ off,
                                                 const int* __restrict__ ghs,
                                                 const float* __restrict__ dinv,
                                                 int2* __restrict__ recs,
                                                 int n, int E, int nbk) {
  __shared__ int cur[64];
  int tid = threadIdx.x, k = blockIdx.x;
  if (tid < 64) {
    int node = k * 64 + tid;
    cur[tid] = (node < n) ? off[node] : 0;
  }
  int e0 = ghs[k * NB1];
  int e1 = (k + 1 < nbk) ? ghs[(k + 1) * NB1] : E;
  __syncthreads();
  for (int i = e0 + tid; i < e1; i += 256) {
    int2 t = tmp[i];
    int pos = atomicAdd(&cur[t.y & 63], 1);
    float w = dinv[t.x] * dinv[t.y];
    recs[pos] = make_int2(t.x, __float_as_int(w));
  }
}

// ---------------- layer 0: propagate 6-dim features ----------------
__global__ void prop6_kernel(const float* __restrict__ x, const int* __restrict__ off,
                             const int2* __restrict__ recs,
                             const float* __restrict__ dinv, float* __restrict__ aggx, int n) {
  int g = (blockIdx.x * blockDim.x + threadIdx.x) >> 3;
  int l = threadIdx.x & 7;
  if (g >= n) return;
  float di = dinv[g];
  float acc = 0.f;
  if (l < 6) acc = di * di * x[g * 6 + l];
  int e0 = off[g], e1 = off[g + 1];
  int e = e0;
  for (; e + 4 <= e1; e += 4) {
    int2 r0 = recs[e], r1 = recs[e + 1], r2 = recs[e + 2], r3 = recs[e + 3];
    float u0 = 0.f, u1 = 0.f, u2 = 0.f, u3 = 0.f;
    if (l < 6) {
      u0 = x[r0.x * 6 + l]; u1 = x[r1.x * 6 + l];
      u2 = x[r2.x * 6 + l]; u3 = x[r3.x * 6 + l];
    }
    acc += __int_as_float(r0.y) * u0 + __int_as_float(r1.y) * u1 +
           __int_as_float(r2.y) * u2 + __int_as_float(r3.y) * u3;
  }
  for (; e < e1; ++e) {
    int2 r = recs[e];
    if (l < 6) acc += __int_as_float(r.y) * x[r.x * 6 + l];
  }
  if (l < 6) aggx[g * 6 + l] = acc;
}

// h0 = relu(aggx @ W0 + b0): [n,6]x[6,128] -> bf16. 16 nodes per 256-block.
__global__ __launch_bounds__(256) void gemm0_kernel(const float* __restrict__ aggx,
                                                    const float* __restrict__ W0,
                                                    const float* __restrict__ b0,
                                                    unsigned short* __restrict__ out, int n) {
  __shared__ float Ws[6 * 128];
  __shared__ float bs[128];
  for (int i = threadIdx.x; i < 6 * 128; i += 256) Ws[i] = W0[i];
  if (threadIdx.x < 128) bs[threadIdx.x] = b0[threadIdx.x];
  __syncthreads();
  int f = threadIdx.x & 127;
  int h = threadIdx.x >> 7;
  int base = blockIdx.x * 16;
#pragma unroll
  for (int j = 0; j < 8; ++j) {
    int nd = base + h * 8 + j;
    if (nd < n) {
      float acc = bs[f];
#pragma unroll
      for (int k = 0; k < 6; ++k) acc += aggx[nd * 6 + k] * Ws[k * 128 + f];
      out[(size_t)nd * HDIM + f] = bf16rn(fmaxf(acc, 0.f));
    }
  }
}

// ---------------- weight prep: fp32 W[128][128] -> bf16 fragment order -----
__global__ __launch_bounds__(256) void wprep_kernel(const float* __restrict__ w1,
                                                    const float* __restrict__ w2,
                                                    const float* __restrict__ rw0,
                                                    const float* __restrict__ rw1,
                                                    unsigned short* __restrict__ wtf) {
  int widx = blockIdx.y;
  const float* W = (widx == 0) ? w1 : (widx == 1) ? w2 : (widx == 2) ? rw0 : rw1;
  int c = blockIdx.x * 256 + threadIdx.x;  // 0..2047
  int l = c & 63, kk = (c >> 6) & 3, ft = c >> 8;
  int f = ft * 16 + (l & 15);
  int k0 = kk * 32 + ((l >> 4) << 3);
  unsigned short v[8];
#pragma unroll
  for (int j = 0; j < 8; ++j) v[j] = bf16rn(W[(size_t)(k0 + j) * 128 + f]);
  uint4 pk;
  pk.x = (unsigned)v[0] | ((unsigned)v[1] << 16);
  pk.y = (unsigned)v[2] | ((unsigned)v[3] << 16);
  pk.z = (unsigned)v[4] | ((unsigned)v[5] << 16);
  pk.w = (unsigned)v[6] | ((unsigned)v[7] << 16);
  *(uint4*)&wtf[((size_t)widx * 16384) + (size_t)c * 8] = pk;
}

// ---------------- MFMA GEMM: [n,128](bf16) @ W[128,128] ----------------
// ACT: 0 = raw -> bf16 out; 2 = bias+leaky -> bf16 out;
//      3 = bias+leaky, dot rw2, +rb2 -> fp32 out1[n]
template <int ACT>
__global__ __launch_bounds__(256) void mgemm_kernel(const unsigned short* __restrict__ in,
                                                    const unsigned short* __restrict__ wtf,
                                                    const float* __restrict__ bias,
                                                    unsigned short* __restrict__ out, int n,
                                                    const float* __restrict__ rw2,
                                                    const float* __restrict__ rb2,
                                                    float* __restrict__ out1) {
  __shared__ unsigned short Alds[8192];   // 16KB: swizzled A tile
  __shared__ unsigned short Wlds[16384];  // 32KB fragment-ordered
  int tid = threadIdx.x;
  int rowBase = blockIdx.x * 64;
  {
    const uint4* src = (const uint4*)wtf;
    uint4* dst = (uint4*)Wlds;
#pragma unroll
    for (int c = 0; c < 8; ++c) dst[c * 256 + tid] = src[c * 256 + tid];
  }
  {
    int k8 = tid & 15, tr = tid >> 4;
#pragma unroll
    for (int c = 0; c < 4; ++c) {
      int row = tr + c * 16;
      int gr = rowBase + row;
      uint4 v = make_uint4(0u, 0u, 0u, 0u);
      if (gr < n) v = *(const uint4*)&in[(size_t)gr * HDIM + k8 * 8];
      int srow = row ^ (k8 & 7);
      *(uint4*)&Alds[k8 * 512 + srow * 8] = v;
    }
  }
  __syncthreads();
  int wv = tid >> 6, lane = tid & 63;
  int l16 = lane >> 4, fcol = lane & 15;
  int lrow = wv * 16 + fcol;
  bf16x8 af[4];
#pragma unroll
  for (int kk = 0; kk < 4; ++kk) {
    int k8 = kk * 4 + l16;
    int srow = lrow ^ (k8 & 7);
    af[kk] = *(const bf16x8*)&Alds[k8 * 512 + srow * 8];
  }
  f32x4 acc[8];
#pragma unroll
  for (int ft = 0; ft < 8; ++ft) acc[ft] = (f32x4)(0.f);
#pragma unroll
  for (int ft = 0; ft < 8; ++ft) {
#pragma unroll
    for (int kk = 0; kk < 4; ++kk) {
      bf16x8 bfr = *(const bf16x8*)&Wlds[(((ft * 4 + kk) * 64) + lane) * 8];
      acc[ft] = __builtin_amdgcn_mfma_f32_16x16x32_bf16(af[kk], bfr, acc[ft], 0, 0, 0);
    }
  }
  int orow0 = rowBase + wv * 16 + l16 * 4;  // D: col=lane&15, row=(lane>>4)*4+reg

  if (ACT == 3) {
    float p[4] = {0.f, 0.f, 0.f, 0.f};
#pragma unroll
    for (int ft = 0; ft < 8; ++ft) {
      int f = ft * 16 + fcol;
      float bb = bias[f], ww = rw2[f];
#pragma unroll
      for (int r = 0; r < 4; ++r) {
        float v = acc[ft][r] + bb;
        v = v > 0.f ? v : 0.01f * v;
        p[r] += v * ww;
      }
    }
#pragma unroll
    for (int d = 1; d < 16; d <<= 1) {
#pragma unroll
      for (int r = 0; r < 4; ++r) p[r] += __shfl_xor(p[r], d, 64);
    }
    if (fcol == 0) {
      float rb = rb2[0];
#pragma unroll
      for (int r = 0; r < 4; ++r) {
        int row = orow0 + r;
        if (row < n) out1[row] = p[r] + rb;
      }
    }
    return;
  }

#pragma unroll
  for (int ft = 0; ft < 8; ++ft) {
    int f = ft * 16 + fcol;
    float bb = (ACT == 2) ? bias[f] : 0.f;
#pragma unroll
    for (int r = 0; r < 4; ++r) {
      int row = orow0 + r;
      if (row < n) {
        float v = acc[ft][r];
        if (ACT == 2) {
          v += bb;
          v = v > 0.f ? v : 0.01f * v;
        }
        out[(size_t)row * HDIM + f] = bf16rn(v);
      }
    }
  }
}

// ---------------- aggregation (pull, CSR): one wave per node, bf16 table ----
__global__ __launch_bounds__(256) void aggregate_kernel(const unsigned short* __restrict__ t,
                                                        const int* __restrict__ off,
                                                        const int2* __restrict__ recs,
                                                        const float* __restrict__ dinv,
                                                        const float* __restrict__ bias,
                                                        unsigned short* __restrict__ out, int n) {
  int node = (blockIdx.x * blockDim.x + threadIdx.x) >> 6;
  int lane = threadIdx.x & 63;
  if (node >= n) return;
  const ushort2* tf = (const ushort2*)t + lane;  // row r at tf[r*64]
  float di = dinv[node];
  float self = di * di;
  ushort2 v = tf[(size_t)node * 64];
  float ax = self * bf16tof(v.x), ay = self * bf16tof(v.y);
  int e0 = off[node], e1 = off[node + 1];
  int e = e0;
  for (; e + 8 <= e1; e += 8) {
    int2 r[8];
    ushort2 u[8];
#pragma unroll
    for (int j = 0; j < 8; ++j) r[j] = recs[e + j];
#pragma unroll
    for (int j = 0; j < 8; ++j) u[j] = tf[(size_t)r[j].x * 64];
#pragma unroll
    for (int j = 0; j < 8; ++j) {
      float w = __int_as_float(r[j].y);
      ax += w * bf16tof(u[j].x);
      ay += w * bf16tof(u[j].y);
    }
  }
  for (; e < e1; ++e) {
    int2 r = recs[e];
    float w = __int_as_float(r.y);
    ushort2 u = tf[(size_t)r.x * 64];
    ax += w * bf16tof(u.x);
    ay += w * bf16tof(u.y);
  }
  const float2* bf = (const float2*)bias + lane;
  float2 b = *bf;
  ax = fmaxf(ax + b.x, 0.f);
  ay = fmaxf(ay + b.y, 0.f);
  ushort2 o;
  o.x = bf16rn(ax);
  o.y = bf16rn(ay);
  *((ushort2*)out + (size_t)node * 64 + lane) = o;
}

// ---------------- host ----------------

static inline size_t align256(size_t x) { return (x + 255) & ~(size_t)255; }

extern "C" void kernel_launch(void* const* d_in, const int* in_sizes, int n_in,
                              void* d_out, int out_size, void* d_ws, size_t ws_size,
                              hipStream_t stream) {
  const float* x   = (const float*)d_in[0];
  const int*   ei  = (const int*)d_in[1];
  const float* W0  = (const float*)d_in[2];
  const float* b0  = (const float*)d_in[3];
  const float* W1  = (const float*)d_in[4];
  const float* b1  = (const float*)d_in[5];
  const float* W2  = (const float*)d_in[6];
  const float* b2  = (const float*)d_in[7];
  const float* Rw0 = (const float*)d_in[8];
  const float* Rb0 = (const float*)d_in[9];
  const float* Rw1 = (const float*)d_in[10];
  const float* Rb1 = (const float*)d_in[11];
  const float* Rw2 = (const float*)d_in[12];
  const float* Rb2 = (const float*)d_in[13];
  float* out = (float*)d_out;

  int N = in_sizes[0] / 6;
  int E = in_sizes[1] / 2;
  int NB = (N + 255) / 256;
  int NBK = (N + 63) >> 6;           // 64-node buckets
  int M = NBK * NB1;
  int chunk = (E + NB1 - 1) / NB1;

  char* p = (char*)d_ws;
  size_t o = 0;
  int* deg     = (int*)(p + o); o = align256(o + (size_t)N * 4);
  int* off     = (int*)(p + o); o = align256(o + (size_t)(N + 1) * 4);
  float* dinv  = (float*)(p + o); o = align256(o + (size_t)N * 4);
  int* bsums   = (int*)(p + o); o = align256(o + (size_t)NB * 4);
  int* bscan   = (int*)(p + o); o = align256(o + (size_t)NB * 4);
  int* gh      = (int*)(p + o); o = align256(o + (size_t)M * 4);
  int* ghs     = (int*)(p + o); o = align256(o + (size_t)M * 4);
  int2* tmp    = (int2*)(p + o); o = align256(o + (size_t)E * 8);
  int2* recs   = (int2*)(p + o); o = align256(o + (size_t)E * 8);
  float* aggx  = (float*)(p + o); o = align256(o + (size_t)N * 6 * 4);
  unsigned short* Wtf = (unsigned short*)(p + o); o = align256(o + (size_t)4 * 16384 * 2);
  unsigned short* H0  = (unsigned short*)(p + o); o = align256(o + (size_t)N * HDIM * 2);
  unsigned short* H1  = (unsigned short*)(p + o); o = align256(o + (size_t)N * HDIM * 2);
  (void)ws_size;

  // degree / dinv / node offsets
  init_deg<<<(N + 255) / 256, 256, 0, stream>>>(deg, N);
  hist_kernel<<<(E + 255) / 256, 256, 0, stream>>>(ei, E, deg);
  dinv_kernel<<<(N + 255) / 256, 256, 0, stream>>>(deg, dinv, N);
  block_sums_kernel<<<NB, 256, 0, stream>>>(deg, bsums, N);
  scan_bsums_kernel<<<1, 256, 0, stream>>>(bsums, bscan, NB);
  write_off_kernel<<<NB, 256, 0, stream>>>(deg, bscan, off, N);

  // 2-level counting sort (replaces atomic scatter fill)
  bucket_hist<<<NB1, 1024, 0, stream>>>(ei, E, chunk, gh, NBK);
  gscan_kernel<<<1, 256, 0, stream>>>(gh, ghs, M);
  bucket_place<<<NB1, 1024, 0, stream>>>(ei, E, chunk, ghs, tmp, NBK);
  fine_sort<<<NBK, 256, 0, stream>>>(tmp, off, ghs, dinv, recs, N, E, NBK);

  // weight prep (independent)
  {
    dim3 g(8, 4);
    wprep_kernel<<<g, 256, 0, stream>>>(W1, W2, Rw0, Rw1, Wtf);
  }

  // layer 0: propagate in 6-dim, then 6->128 gemm + relu -> bf16
  prop6_kernel<<<(N + 31) / 32, 256, 0, stream>>>(x, off, recs, dinv, aggx, N);
  gemm0_kernel<<<(N + 15) / 16, 256, 0, stream>>>(aggx, W0, b0, H0, N);

  int mGrid = (N + 63) / 64;
  int aggGrid = (N + 3) / 4;

  // conv1
  mgemm_kernel<0><<<mGrid, 256, 0, stream>>>(H0, Wtf + 0 * 16384, nullptr, H1, N, nullptr, nullptr, nullptr);
  aggregate_kernel<<<aggGrid, 256, 0, stream>>>(H1, off, recs, dinv, b1, H0, N);
  // conv2
  mgemm_kernel<0><<<mGrid, 256, 0, stream>>>(H0, Wtf + 1 * 16384, nullptr, H1, N, nullptr, nullptr, nullptr);
  aggregate_kernel<<<aggGrid, 256, 0, stream>>>(H1, off, recs, dinv, b2, H0, N);
  // MLP head
  mgemm_kernel<2><<<mGrid, 256, 0, stream>>>(H0, Wtf + 2 * 16384, Rb0, H1, N, nullptr, nullptr, nullptr);
  mgemm_kernel<3><<<mGrid, 256, 0, stream>>>(H1, Wtf + 3 * 16384, Rb1, nullptr, N, Rw2, Rb2, out);
}

// Round 14
// 337.156 us; speedup vs baseline: 1.2741x; 1.2741x over previous
//
#include <hip/hip_runtime.h>

// GCN on MI355X. R13 (resubmitted after infra failure) = R12 with the
// 100K-entry gh-scan parallelized (R12's single-block gscan serialized at
// 101us, 0.04% occupancy).
// 3-stage scan: chunk sums (391 blocks) -> 1-block scan of sums -> rescan+base.

#define HDIM 128
#define NB1 128  // sort blocks (level-1)

typedef __attribute__((ext_vector_type(8))) short bf16x8;
typedef __attribute__((ext_vector_type(4))) float f32x4;

__device__ inline unsigned short bf16rn(float f) {
  unsigned u = __float_as_uint(f);
  unsigned r = (u + 0x7FFFu + ((u >> 16) & 1u)) >> 16;
  return (unsigned short)r;
}
__device__ inline float bf16tof(unsigned short h) {
  return __uint_as_float(((unsigned)h) << 16);
}

// ---------------- degree / dinv ----------------

__global__ void init_deg(int* deg, int n) {
  int i = blockIdx.x * blockDim.x + threadIdx.x;
  if (i < n) deg[i] = 1;  // self loop
}

__global__ void hist_kernel(const int* __restrict__ ei, int E, int* __restrict__ deg) {
  int e = blockIdx.x * blockDim.x + threadIdx.x;
  if (e < E) atomicAdd(&deg[ei[E + e]], 1);  // dst = ei[1][e]
}

__global__ void dinv_kernel(const int* __restrict__ deg, float* __restrict__ dinv, int n) {
  int i = blockIdx.x * blockDim.x + threadIdx.x;
  if (i < n) dinv[i] = rsqrtf((float)deg[i]);
}

// ---------------- generic 3-stage parallel exclusive scan ----------------

// stage A: per-256-chunk sums. mode 0: in[i]; mode 1: in[i]-1 (deg).
template <int MODE>
__global__ __launch_bounds__(256) void chunk_sums_kernel(const int* __restrict__ in,
                                                         int* __restrict__ sums, int M) {
  int i = blockIdx.x * 256 + threadIdx.x;
  int v = (i < M) ? (MODE ? in[i] - 1 : in[i]) : 0;
#pragma unroll
  for (int d = 1; d < 64; d <<= 1) v += __shfl_xor(v, d, 64);
  __shared__ int ws[4];
  int lane = threadIdx.x & 63, wid = threadIdx.x >> 6;
  if (lane == 0) ws[wid] = v;
  __syncthreads();
  if (threadIdx.x == 0) sums[blockIdx.x] = ws[0] + ws[1] + ws[2] + ws[3];
}

// stage B: single-block chunked exclusive scan (small M, <=4096 fast)
__global__ __launch_bounds__(256) void small_scan_kernel(const int* __restrict__ in,
                                                         int* __restrict__ outv, int M) {
  __shared__ int wsum[4];
  __shared__ int carry_s;
  int tid = threadIdx.x, lane = tid & 63, wid = tid >> 6;
  if (tid == 0) carry_s = 0;
  __syncthreads();
  int nchunks = (M + 4095) / 4096;
  for (int c = 0; c < nchunks; ++c) {
    int base = c * 4096 + tid * 16;
    int v[16];
#pragma unroll
    for (int j = 0; j < 16; ++j) {
      int i = base + j;
      v[j] = (i < M) ? in[i] : 0;
    }
    int s = 0;
#pragma unroll
    for (int j = 0; j < 16; ++j) { int t = v[j]; v[j] = s; s += t; }
    int tot = s;
    int inc = tot;
#pragma unroll
    for (int d = 1; d < 64; d <<= 1) {
      int t = __shfl_up(inc, (unsigned)d, 64);
      if (lane >= d) inc += t;
    }
    if (lane == 63) wsum[wid] = inc;
    int texcl = inc - tot;
    __syncthreads();
    int wexcl = 0, ctot = 0;
#pragma unroll
    for (int w = 0; w < 4; ++w) {
      int ws = wsum[w];
      if (w < wid) wexcl += ws;
      ctot += ws;
    }
    int cbase = carry_s + wexcl + texcl;
#pragma unroll
    for (int j = 0; j < 16; ++j) {
      int i = base + j;
      if (i < M) outv[i] = cbase + v[j];
    }
    __syncthreads();
    if (tid == 0) carry_s += ctot;
    __syncthreads();
  }
}

// stage C: per-chunk exclusive rescan + base. MODE as stage A.
template <int MODE, int WRITE_TOTAL>
__global__ __launch_bounds__(256) void write_scan_kernel(const int* __restrict__ in,
                                                         const int* __restrict__ bases,
                                                         int* __restrict__ outv, int M) {
  int i = blockIdx.x * 256 + threadIdx.x;
  int v = (i < M) ? (MODE ? in[i] - 1 : in[i]) : 0;
  int lane = threadIdx.x & 63, wid = threadIdx.x >> 6;
  int inc = v;
#pragma unroll
  for (int d = 1; d < 64; d <<= 1) {
    int t = __shfl_up(inc, (unsigned)d, 64);
    if (lane >= d) inc += t;
  }
  __shared__ int ws[4];
  if (lane == 63) ws[wid] = inc;
  __syncthreads();
  int woff = 0;
  for (int w = 0; w < wid; ++w) woff += ws[w];
  inc += woff;
  int base = bases[blockIdx.x];
  if (i < M) {
    outv[i] = base + inc - v;
    if (WRITE_TOTAL && i == M - 1) outv[M] = base + inc;
  }
}

// ---------------- 2-level counting sort ----------------

__global__ __launch_bounds__(1024) void bucket_hist(const int* __restrict__ ei, int E,
                                                    int chunk, int* __restrict__ gh, int nbk) {
  __shared__ int h[1024];
  int tid = threadIdx.x, b = blockIdx.x;
  for (int i = tid; i < nbk; i += 1024) h[i] = 0;
  __syncthreads();
  int s = b * chunk, e = min(E, s + chunk);
  for (int i = s + tid; i < e; i += 1024) atomicAdd(&h[ei[E + i] >> 6], 1);
  __syncthreads();
  for (int k = tid; k < nbk; k += 1024) gh[k * NB1 + b] = h[k];
}

__global__ __launch_bounds__(1024) void bucket_place(const int* __restrict__ ei, int E,
                                                     int chunk, const int* __restrict__ ghs,
                                                     int2* __restrict__ tmp, int nbk) {
  __shared__ int cur[1024];
  int tid = threadIdx.x, b = blockIdx.x;
  for (int k = tid; k < nbk; k += 1024) cur[k] = ghs[k * NB1 + b];
  __syncthreads();
  int s = b * chunk, e = min(E, s + chunk);
  for (int i = s + tid; i < e; i += 1024) {
    int src = ei[i], dst = ei[E + i];
    int pos = atomicAdd(&cur[dst >> 6], 1);
    tmp[pos] = make_int2(src, dst);
  }
}

__global__ __launch_bounds__(256) void fine_sort(const int2* __restrict__ tmp,
                                                 const int* __restrict__ off,
                                                 const int* __restrict__ ghs,
                                                 const float* __restrict__ dinv,
                                                 int2* __restrict__ recs,
                                                 int n, int E, int nbk) {
  __shared__ int cur[64];
  int tid = threadIdx.x, k = blockIdx.x;
  if (tid < 64) {
    int node = k * 64 + tid;
    cur[tid] = (node < n) ? off[node] : 0;
  }
  int e0 = ghs[k * NB1];
  int e1 = (k + 1 < nbk) ? ghs[(k + 1) * NB1] : E;
  __syncthreads();
  for (int i = e0 + tid; i < e1; i += 256) {
    int2 t = tmp[i];
    int pos = atomicAdd(&cur[t.y & 63], 1);
    float w = dinv[t.x] * dinv[t.y];
    recs[pos] = make_int2(t.x, __float_as_int(w));
  }
}

// ---------------- layer 0: propagate 6-dim features ----------------
__global__ void prop6_kernel(const float* __restrict__ x, const int* __restrict__ off,
                             const int2* __restrict__ recs,
                             const float* __restrict__ dinv, float* __restrict__ aggx, int n) {
  int g = (blockIdx.x * blockDim.x + threadIdx.x) >> 3;
  int l = threadIdx.x & 7;
  if (g >= n) return;
  float di = dinv[g];
  float acc = 0.f;
  if (l < 6) acc = di * di * x[g * 6 + l];
  int e0 = off[g], e1 = off[g + 1];
  int e = e0;
  for (; e + 4 <= e1; e += 4) {
    int2 r0 = recs[e], r1 = recs[e + 1], r2 = recs[e + 2], r3 = recs[e + 3];
    float u0 = 0.f, u1 = 0.f, u2 = 0.f, u3 = 0.f;
    if (l < 6) {
      u0 = x[r0.x * 6 + l]; u1 = x[r1.x * 6 + l];
      u2 = x[r2.x * 6 + l]; u3 = x[r3.x * 6 + l];
    }
    acc += __int_as_float(r0.y) * u0 + __int_as_float(r1.y) * u1 +
           __int_as_float(r2.y) * u2 + __int_as_float(r3.y) * u3;
  }
  for (; e < e1; ++e) {
    int2 r = recs[e];
    if (l < 6) acc += __int_as_float(r.y) * x[r.x * 6 + l];
  }
  if (l < 6) aggx[g * 6 + l] = acc;
}

// h0 = relu(aggx @ W0 + b0): [n,6]x[6,128] -> bf16. 16 nodes per 256-block.
__global__ __launch_bounds__(256) void gemm0_kernel(const float* __restrict__ aggx,
                                                    const float* __restrict__ W0,
                                                    const float* __restrict__ b0,
                                                    unsigned short* __restrict__ out, int n) {
  __shared__ float Ws[6 * 128];
  __shared__ float bs[128];
  for (int i = threadIdx.x; i < 6 * 128; i += 256) Ws[i] = W0[i];
  if (threadIdx.x < 128) bs[threadIdx.x] = b0[threadIdx.x];
  __syncthreads();
  int f = threadIdx.x & 127;
  int h = threadIdx.x >> 7;
  int base = blockIdx.x * 16;
#pragma unroll
  for (int j = 0; j < 8; ++j) {
    int nd = base + h * 8 + j;
    if (nd < n) {
      float acc = bs[f];
#pragma unroll
      for (int k = 0; k < 6; ++k) acc += aggx[nd * 6 + k] * Ws[k * 128 + f];
      out[(size_t)nd * HDIM + f] = bf16rn(fmaxf(acc, 0.f));
    }
  }
}

// ---------------- weight prep: fp32 W[128][128] -> bf16 fragment order -----
__global__ __launch_bounds__(256) void wprep_kernel(const float* __restrict__ w1,
                                                    const float* __restrict__ w2,
                                                    const float* __restrict__ rw0,
                                                    const float* __restrict__ rw1,
                                                    unsigned short* __restrict__ wtf) {
  int widx = blockIdx.y;
  const float* W = (widx == 0) ? w1 : (widx == 1) ? w2 : (widx == 2) ? rw0 : rw1;
  int c = blockIdx.x * 256 + threadIdx.x;  // 0..2047
  int l = c & 63, kk = (c >> 6) & 3, ft = c >> 8;
  int f = ft * 16 + (l & 15);
  int k0 = kk * 32 + ((l >> 4) << 3);
  unsigned short v[8];
#pragma unroll
  for (int j = 0; j < 8; ++j) v[j] = bf16rn(W[(size_t)(k0 + j) * 128 + f]);
  uint4 pk;
  pk.x = (unsigned)v[0] | ((unsigned)v[1] << 16);
  pk.y = (unsigned)v[2] | ((unsigned)v[3] << 16);
  pk.z = (unsigned)v[4] | ((unsigned)v[5] << 16);
  pk.w = (unsigned)v[6] | ((unsigned)v[7] << 16);
  *(uint4*)&wtf[((size_t)widx * 16384) + (size_t)c * 8] = pk;
}

// ---------------- MFMA GEMM: [n,128](bf16) @ W[128,128] ----------------
template <int ACT>
__global__ __launch_bounds__(256) void mgemm_kernel(const unsigned short* __restrict__ in,
                                                    const unsigned short* __restrict__ wtf,
                                                    const float* __restrict__ bias,
                                                    unsigned short* __restrict__ out, int n,
                                                    const float* __restrict__ rw2,
                                                    const float* __restrict__ rb2,
                                                    float* __restrict__ out1) {
  __shared__ unsigned short Alds[8192];   // 16KB: swizzled A tile
  __shared__ unsigned short Wlds[16384];  // 32KB fragment-ordered
  int tid = threadIdx.x;
  int rowBase = blockIdx.x * 64;
  {
    const uint4* src = (const uint4*)wtf;
    uint4* dst = (uint4*)Wlds;
#pragma unroll
    for (int c = 0; c < 8; ++c) dst[c * 256 + tid] = src[c * 256 + tid];
  }
  {
    int k8 = tid & 15, tr = tid >> 4;
#pragma unroll
    for (int c = 0; c < 4; ++c) {
      int row = tr + c * 16;
      int gr = rowBase + row;
      uint4 v = make_uint4(0u, 0u, 0u, 0u);
      if (gr < n) v = *(const uint4*)&in[(size_t)gr * HDIM + k8 * 8];
      int srow = row ^ (k8 & 7);
      *(uint4*)&Alds[k8 * 512 + srow * 8] = v;
    }
  }
  __syncthreads();
  int wv = tid >> 6, lane = tid & 63;
  int l16 = lane >> 4, fcol = lane & 15;
  int lrow = wv * 16 + fcol;
  bf16x8 af[4];
#pragma unroll
  for (int kk = 0; kk < 4; ++kk) {
    int k8 = kk * 4 + l16;
    int srow = lrow ^ (k8 & 7);
    af[kk] = *(const bf16x8*)&Alds[k8 * 512 + srow * 8];
  }
  f32x4 acc[8];
#pragma unroll
  for (int ft = 0; ft < 8; ++ft) acc[ft] = (f32x4)(0.f);
#pragma unroll
  for (int ft = 0; ft < 8; ++ft) {
#pragma unroll
    for (int kk = 0; kk < 4; ++kk) {
      bf16x8 bfr = *(const bf16x8*)&Wlds[(((ft * 4 + kk) * 64) + lane) * 8];
      acc[ft] = __builtin_amdgcn_mfma_f32_16x16x32_bf16(af[kk], bfr, acc[ft], 0, 0, 0);
    }
  }
  int orow0 = rowBase + wv * 16 + l16 * 4;  // D: col=lane&15, row=(lane>>4)*4+reg

  if (ACT == 3) {
    float p[4] = {0.f, 0.f, 0.f, 0.f};
#pragma unroll
    for (int ft = 0; ft < 8; ++ft) {
      int f = ft * 16 + fcol;
      float bb = bias[f], ww = rw2[f];
#pragma unroll
      for (int r = 0; r < 4; ++r) {
        float v = acc[ft][r] + bb;
        v = v > 0.f ? v : 0.01f * v;
        p[r] += v * ww;
      }
    }
#pragma unroll
    for (int d = 1; d < 16; d <<= 1) {
#pragma unroll
      for (int r = 0; r < 4; ++r) p[r] += __shfl_xor(p[r], d, 64);
    }
    if (fcol == 0) {
      float rb = rb2[0];
#pragma unroll
      for (int r = 0; r < 4; ++r) {
        int row = orow0 + r;
        if (row < n) out1[row] = p[r] + rb;
      }
    }
    return;
  }

#pragma unroll
  for (int ft = 0; ft < 8; ++ft) {
    int f = ft * 16 + fcol;
    float bb = (ACT == 2) ? bias[f] : 0.f;
#pragma unroll
    for (int r = 0; r < 4; ++r) {
      int row = orow0 + r;
      if (row < n) {
        float v = acc[ft][r];
        if (ACT == 2) {
          v += bb;
          v = v > 0.f ? v : 0.01f * v;
        }
        out[(size_t)row * HDIM + f] = bf16rn(v);
      }
    }
  }
}

// ---------------- aggregation (pull, CSR): one wave per node, bf16 table ----
__global__ __launch_bounds__(256) void aggregate_kernel(const unsigned short* __restrict__ t,
                                                        const int* __restrict__ off,
                                                        const int2* __restrict__ recs,
                                                        const float* __restrict__ dinv,
                                                        const float* __restrict__ bias,
                                                        unsigned short* __restrict__ out, int n) {
  int node = (blockIdx.x * blockDim.x + threadIdx.x) >> 6;
  int lane = threadIdx.x & 63;
  if (node >= n) return;
  const ushort2* tf = (const ushort2*)t + lane;  // row r at tf[r*64]
  float di = dinv[node];
  float self = di * di;
  ushort2 v = tf[(size_t)node * 64];
  float ax = self * bf16tof(v.x), ay = self * bf16tof(v.y);
  int e0 = off[node], e1 = off[node + 1];
  int e = e0;
  for (; e + 8 <= e1; e += 8) {
    int2 r[8];
    ushort2 u[8];
#pragma unroll
    for (int j = 0; j < 8; ++j) r[j] = recs[e + j];
#pragma unroll
    for (int j = 0; j < 8; ++j) u[j] = tf[(size_t)r[j].x * 64];
#pragma unroll
    for (int j = 0; j < 8; ++j) {
      float w = __int_as_float(r[j].y);
      ax += w * bf16tof(u[j].x);
      ay += w * bf16tof(u[j].y);
    }
  }
  for (; e < e1; ++e) {
    int2 r = recs[e];
    float w = __int_as_float(r.y);
    ushort2 u = tf[(size_t)r.x * 64];
    ax += w * bf16tof(u.x);
    ay += w * bf16tof(u.y);
  }
  const float2* bf = (const float2*)bias + lane;
  float2 b = *bf;
  ax = fmaxf(ax + b.x, 0.f);
  ay = fmaxf(ay + b.y, 0.f);
  ushort2 o;
  o.x = bf16rn(ax);
  o.y = bf16rn(ay);
  *((ushort2*)out + (size_t)node * 64 + lane) = o;
}

// ---------------- host ----------------

static inline size_t align256(size_t x) { return (x + 255) & ~(size_t)255; }

extern "C" void kernel_launch(void* const* d_in, const int* in_sizes, int n_in,
                              void* d_out, int out_size, void* d_ws, size_t ws_size,
                              hipStream_t stream) {
  const float* x   = (const float*)d_in[0];
  const int*   ei  = (const int*)d_in[1];
  const float* W0  = (const float*)d_in[2];
  const float* b0  = (const float*)d_in[3];
  const float* W1  = (const float*)d_in[4];
  const float* b1  = (const float*)d_in[5];
  const float* W2  = (const float*)d_in[6];
  const float* b2  = (const float*)d_in[7];
  const float* Rw0 = (const float*)d_in[8];
  const float* Rb0 = (const float*)d_in[9];
  const float* Rw1 = (const float*)d_in[10];
  const float* Rb1 = (const float*)d_in[11];
  const float* Rw2 = (const float*)d_in[12];
  const float* Rb2 = (const float*)d_in[13];
  float* out = (float*)d_out;

  int N = in_sizes[0] / 6;
  int E = in_sizes[1] / 2;
  int NB = (N + 255) / 256;          // chunks for off-scan
  int NBK = (N + 63) >> 6;           // 64-node buckets
  int M = NBK * NB1;                 // gh entries
  int MB = (M + 255) / 256;          // chunks for gh-scan
  int chunk = (E + NB1 - 1) / NB1;

  char* p = (char*)d_ws;
  size_t o = 0;
  int* deg     = (int*)(p + o); o = align256(o + (size_t)N * 4);
  int* off     = (int*)(p + o); o = align256(o + (size_t)(N + 1) * 4);
  float* dinv  = (float*)(p + o); o = align256(o + (size_t)N * 4);
  int* bsums   = (int*)(p + o); o = align256(o + (size_t)(MB > NB ? MB : NB) * 4);
  int* bscan   = (int*)(p + o); o = align256(o + (size_t)(MB > NB ? MB : NB) * 4);
  int* gh      = (int*)(p + o); o = align256(o + (size_t)M * 4);
  int* ghs     = (int*)(p + o); o = align256(o + (size_t)M * 4);
  int2* tmp    = (int2*)(p + o); o = align256(o + (size_t)E * 8);
  int2* recs   = (int2*)(p + o); o = align256(o + (size_t)E * 8);
  float* aggx  = (float*)(p + o); o = align256(o + (size_t)N * 6 * 4);
  unsigned short* Wtf = (unsigned short*)(p + o); o = align256(o + (size_t)4 * 16384 * 2);
  unsigned short* H0  = (unsigned short*)(p + o); o = align256(o + (size_t)N * HDIM * 2);
  unsigned short* H1  = (unsigned short*)(p + o); o = align256(o + (size_t)N * HDIM * 2);
  (void)ws_size;

  // degree / dinv / node offsets (3-stage scan of deg-1)
  init_deg<<<(N + 255) / 256, 256, 0, stream>>>(deg, N);
  hist_kernel<<<(E + 255) / 256, 256, 0, stream>>>(ei, E, deg);
  dinv_kernel<<<(N + 255) / 256, 256, 0, stream>>>(deg, dinv, N);
  chunk_sums_kernel<1><<<NB, 256, 0, stream>>>(deg, bsums, N);
  small_scan_kernel<<<1, 256, 0, stream>>>(bsums, bscan, NB);
  write_scan_kernel<1, 1><<<NB, 256, 0, stream>>>(deg, bscan, off, N);

  // 2-level counting sort with parallel gh-scan
  bucket_hist<<<NB1, 1024, 0, stream>>>(ei, E, chunk, gh, NBK);
  chunk_sums_kernel<0><<<MB, 256, 0, stream>>>(gh, bsums, M);
  small_scan_kernel<<<1, 256, 0, stream>>>(bsums, bscan, MB);
  write_scan_kernel<0, 0><<<MB, 256, 0, stream>>>(gh, bscan, ghs, M);
  bucket_place<<<NB1, 1024, 0, stream>>>(ei, E, chunk, ghs, tmp, NBK);
  fine_sort<<<NBK, 256, 0, stream>>>(tmp, off, ghs, dinv, recs, N, E, NBK);

  // weight prep (independent)
  {
    dim3 g(8, 4);
    wprep_kernel<<<g, 256, 0, stream>>>(W1, W2, Rw0, Rw1, Wtf);
  }

  // layer 0: propagate in 6-dim, then 6->128 gemm + relu -> bf16
  prop6_kernel<<<(N + 31) / 32, 256, 0, stream>>>(x, off, recs, dinv, aggx, N);
  gemm0_kernel<<<(N + 15) / 16, 256, 0, stream>>>(aggx, W0, b0, H0, N);

  int mGrid = (N + 63) / 64;
  int aggGrid = (N + 3) / 4;

  // conv1
  mgemm_kernel<0><<<mGrid, 256, 0, stream>>>(H0, Wtf + 0 * 16384, nullptr, H1, N, nullptr, nullptr, nullptr);
  aggregate_kernel<<<aggGrid, 256, 0, stream>>>(H1, off, recs, dinv, b1, H0, N);
  // conv2
  mgemm_kernel<0><<<mGrid, 256, 0, stream>>>(H0, Wtf + 1 * 16384, nullptr, H1, N, nullptr, nullptr, nullptr);
  aggregate_kernel<<<aggGrid, 256, 0, stream>>>(H1, off, recs, dinv, b2, H0, N);
  // MLP head
  mgemm_kernel<2><<<mGrid, 256, 0, stream>>>(H0, Wtf + 2 * 16384, Rb0, H1, N, nullptr, nullptr, nullptr);
  mgemm_kernel<3><<<mGrid, 256, 0, stream>>>(H1, Wtf + 3 * 16384, Rb1, nullptr, N, Rw2, Rb2, out);
}

// Round 15
// 257.991 us; speedup vs baseline: 1.6650x; 1.3069x over previous
//
#include <hip/hip_runtime.h>

// GCN on MI355X. R15: degree histogram's 1.6M global atomics (70us, 50MB
// write-through) eliminated — degrees are counted per 64-node bucket from the
// sorted tmp with LDS atomics (fine_count), which also emits off[] directly
// (off[node] = bucket base + in-bucket prefix) and dinv[]. Removes init_deg,
// hist_kernel, dinv_kernel and the 3-kernel deg scan. Consumers unchanged.

#define HDIM 128
#define NB1 128  // sort blocks (level-1)

typedef __attribute__((ext_vector_type(8))) short bf16x8;
typedef __attribute__((ext_vector_type(4))) float f32x4;

__device__ inline unsigned short bf16rn(float f) {
  unsigned u = __float_as_uint(f);
  unsigned r = (u + 0x7FFFu + ((u >> 16) & 1u)) >> 16;
  return (unsigned short)r;
}
__device__ inline float bf16tof(unsigned short h) {
  return __uint_as_float(((unsigned)h) << 16);
}

// ---------------- 3-stage parallel exclusive scan (for gh only) ----------

__global__ __launch_bounds__(256) void chunk_sums_kernel(const int* __restrict__ in,
                                                         int* __restrict__ sums, int M) {
  int i = blockIdx.x * 256 + threadIdx.x;
  int v = (i < M) ? in[i] : 0;
#pragma unroll
  for (int d = 1; d < 64; d <<= 1) v += __shfl_xor(v, d, 64);
  __shared__ int ws[4];
  int lane = threadIdx.x & 63, wid = threadIdx.x >> 6;
  if (lane == 0) ws[wid] = v;
  __syncthreads();
  if (threadIdx.x == 0) sums[blockIdx.x] = ws[0] + ws[1] + ws[2] + ws[3];
}

__global__ __launch_bounds__(256) void small_scan_kernel(const int* __restrict__ in,
                                                         int* __restrict__ outv, int M) {
  __shared__ int wsum[4];
  __shared__ int carry_s;
  int tid = threadIdx.x, lane = tid & 63, wid = tid >> 6;
  if (tid == 0) carry_s = 0;
  __syncthreads();
  int nchunks = (M + 4095) / 4096;
  for (int c = 0; c < nchunks; ++c) {
    int base = c * 4096 + tid * 16;
    int v[16];
#pragma unroll
    for (int j = 0; j < 16; ++j) {
      int i = base + j;
      v[j] = (i < M) ? in[i] : 0;
    }
    int s = 0;
#pragma unroll
    for (int j = 0; j < 16; ++j) { int t = v[j]; v[j] = s; s += t; }
    int tot = s;
    int inc = tot;
#pragma unroll
    for (int d = 1; d < 64; d <<= 1) {
      int t = __shfl_up(inc, (unsigned)d, 64);
      if (lane >= d) inc += t;
    }
    if (lane == 63) wsum[wid] = inc;
    int texcl = inc - tot;
    __syncthreads();
    int wexcl = 0, ctot = 0;
#pragma unroll
    for (int w = 0; w < 4; ++w) {
      int ws = wsum[w];
      if (w < wid) wexcl += ws;
      ctot += ws;
    }
    int cbase = carry_s + wexcl + texcl;
#pragma unroll
    for (int j = 0; j < 16; ++j) {
      int i = base + j;
      if (i < M) outv[i] = cbase + v[j];
    }
    __syncthreads();
    if (tid == 0) carry_s += ctot;
    __syncthreads();
  }
}

__global__ __launch_bounds__(256) void write_scan_kernel(const int* __restrict__ in,
                                                         const int* __restrict__ bases,
                                                         int* __restrict__ outv, int M) {
  int i = blockIdx.x * 256 + threadIdx.x;
  int v = (i < M) ? in[i] : 0;
  int lane = threadIdx.x & 63, wid = threadIdx.x >> 6;
  int inc = v;
#pragma unroll
  for (int d = 1; d < 64; d <<= 1) {
    int t = __shfl_up(inc, (unsigned)d, 64);
    if (lane >= d) inc += t;
  }
  __shared__ int ws[4];
  if (lane == 63) ws[wid] = inc;
  __syncthreads();
  int woff = 0;
  for (int w = 0; w < wid; ++w) woff += ws[w];
  inc += woff;
  int base = bases[blockIdx.x];
  if (i < M) outv[i] = base + inc - v;
}

// ---------------- 2-level counting sort ----------------

__global__ __launch_bounds__(1024) void bucket_hist(const int* __restrict__ ei, int E,
                                                    int chunk, int* __restrict__ gh, int nbk) {
  __shared__ int h[1024];
  int tid = threadIdx.x, b = blockIdx.x;
  for (int i = tid; i < nbk; i += 1024) h[i] = 0;
  __syncthreads();
  int s = b * chunk, e = min(E, s + chunk);
  for (int i = s + tid; i < e; i += 1024) atomicAdd(&h[ei[E + i] >> 6], 1);
  __syncthreads();
  for (int k = tid; k < nbk; k += 1024) gh[k * NB1 + b] = h[k];
}

__global__ __launch_bounds__(1024) void bucket_place(const int* __restrict__ ei, int E,
                                                     int chunk, const int* __restrict__ ghs,
                                                     int2* __restrict__ tmp, int nbk) {
  __shared__ int cur[1024];
  int tid = threadIdx.x, b = blockIdx.x;
  for (int k = tid; k < nbk; k += 1024) cur[k] = ghs[k * NB1 + b];
  __syncthreads();
  int s = b * chunk, e = min(E, s + chunk);
  for (int i = s + tid; i < e; i += 1024) {
    int src = ei[i], dst = ei[E + i];
    int pos = atomicAdd(&cur[dst >> 6], 1);
    tmp[pos] = make_int2(src, dst);
  }
}

// per-bucket degree count from sorted tmp -> off[] (bucket base + prefix),
// dinv[] (rsqrt(deg+1)). 4-copy LDS counters kill intra-wave same-addr serial.
__global__ __launch_bounds__(256) void fine_count(const int2* __restrict__ tmp,
                                                  const int* __restrict__ ghs,
                                                  int* __restrict__ off,
                                                  float* __restrict__ dinv,
                                                  int n, int E, int nbk) {
  __shared__ int cnt[64][4];
  int tid = threadIdx.x, k = blockIdx.x;
  ((int*)cnt)[tid] = 0;
  int e0 = ghs[k * NB1];
  int e1 = (k + 1 < nbk) ? ghs[(k + 1) * NB1] : E;
  __syncthreads();
  for (int i = e0 + tid; i < e1; i += 256)
    atomicAdd(&cnt[tmp[i].y & 63][tid & 3], 1);
  __syncthreads();
  if (tid < 64) {
    int c = cnt[tid][0] + cnt[tid][1] + cnt[tid][2] + cnt[tid][3];
    int inc = c;
#pragma unroll
    for (int d = 1; d < 64; d <<= 1) {
      int t = __shfl_up(inc, (unsigned)d, 64);
      if (tid >= d) inc += t;
    }
    int node = k * 64 + tid;
    if (node < n) {
      off[node] = e0 + inc - c;
      dinv[node] = rsqrtf((float)(c + 1));
      if (node == n - 1) off[n] = e0 + inc;
    }
  }
}

__global__ __launch_bounds__(256) void fine_sort(const int2* __restrict__ tmp,
                                                 const int* __restrict__ off,
                                                 const int* __restrict__ ghs,
                                                 const float* __restrict__ dinv,
                                                 int2* __restrict__ recs,
                                                 int n, int E, int nbk) {
  __shared__ int cur[64];
  int tid = threadIdx.x, k = blockIdx.x;
  if (tid < 64) {
    int node = k * 64 + tid;
    cur[tid] = (node < n) ? off[node] : 0;
  }
  int e0 = ghs[k * NB1];
  int e1 = (k + 1 < nbk) ? ghs[(k + 1) * NB1] : E;
  __syncthreads();
  for (int i = e0 + tid; i < e1; i += 256) {
    int2 t = tmp[i];
    int pos = atomicAdd(&cur[t.y & 63], 1);
    float w = dinv[t.x] * dinv[t.y];
    recs[pos] = make_int2(t.x, __float_as_int(w));
  }
}

// ---------------- layer 0: propagate 6-dim features ----------------
__global__ void prop6_kernel(const float* __restrict__ x, const int* __restrict__ off,
                             const int2* __restrict__ recs,
                             const float* __restrict__ dinv, float* __restrict__ aggx, int n) {
  int g = (blockIdx.x * blockDim.x + threadIdx.x) >> 3;
  int l = threadIdx.x & 7;
  if (g >= n) return;
  float di = dinv[g];
  float acc = 0.f;
  if (l < 6) acc = di * di * x[g * 6 + l];
  int e0 = off[g], e1 = off[g + 1];
  int e = e0;
  for (; e + 4 <= e1; e += 4) {
    int2 r0 = recs[e], r1 = recs[e + 1], r2 = recs[e + 2], r3 = recs[e + 3];
    float u0 = 0.f, u1 = 0.f, u2 = 0.f, u3 = 0.f;
    if (l < 6) {
      u0 = x[r0.x * 6 + l]; u1 = x[r1.x * 6 + l];
      u2 = x[r2.x * 6 + l]; u3 = x[r3.x * 6 + l];
    }
    acc += __int_as_float(r0.y) * u0 + __int_as_float(r1.y) * u1 +
           __int_as_float(r2.y) * u2 + __int_as_float(r3.y) * u3;
  }
  for (; e < e1; ++e) {
    int2 r = recs[e];
    if (l < 6) acc += __int_as_float(r.y) * x[r.x * 6 + l];
  }
  if (l < 6) aggx[g * 6 + l] = acc;
}

// h0 = relu(aggx @ W0 + b0): [n,6]x[6,128] -> bf16. 16 nodes per 256-block.
__global__ __launch_bounds__(256) void gemm0_kernel(const float* __restrict__ aggx,
                                                    const float* __restrict__ W0,
                                                    const float* __restrict__ b0,
                                                    unsigned short* __restrict__ out, int n) {
  __shared__ float Ws[6 * 128];
  __shared__ float bs[128];
  for (int i = threadIdx.x; i < 6 * 128; i += 256) Ws[i] = W0[i];
  if (threadIdx.x < 128) bs[threadIdx.x] = b0[threadIdx.x];
  __syncthreads();
  int f = threadIdx.x & 127;
  int h = threadIdx.x >> 7;
  int base = blockIdx.x * 16;
#pragma unroll
  for (int j = 0; j < 8; ++j) {
    int nd = base + h * 8 + j;
    if (nd < n) {
      float acc = bs[f];
#pragma unroll
      for (int k = 0; k < 6; ++k) acc += aggx[nd * 6 + k] * Ws[k * 128 + f];
      out[(size_t)nd * HDIM + f] = bf16rn(fmaxf(acc, 0.f));
    }
  }
}

// ---------------- weight prep: fp32 W[128][128] -> bf16 fragment order -----
__global__ __launch_bounds__(256) void wprep_kernel(const float* __restrict__ w1,
                                                    const float* __restrict__ w2,
                                                    const float* __restrict__ rw0,
                                                    const float* __restrict__ rw1,
                                                    unsigned short* __restrict__ wtf) {
  int widx = blockIdx.y;
  const float* W = (widx == 0) ? w1 : (widx == 1) ? w2 : (widx == 2) ? rw0 : rw1;
  int c = blockIdx.x * 256 + threadIdx.x;  // 0..2047
  int l = c & 63, kk = (c >> 6) & 3, ft = c >> 8;
  int f = ft * 16 + (l & 15);
  int k0 = kk * 32 + ((l >> 4) << 3);
  unsigned short v[8];
#pragma unroll
  for (int j = 0; j < 8; ++j) v[j] = bf16rn(W[(size_t)(k0 + j) * 128 + f]);
  uint4 pk;
  pk.x = (unsigned)v[0] | ((unsigned)v[1] << 16);
  pk.y = (unsigned)v[2] | ((unsigned)v[3] << 16);
  pk.z = (unsigned)v[4] | ((unsigned)v[5] << 16);
  pk.w = (unsigned)v[6] | ((unsigned)v[7] << 16);
  *(uint4*)&wtf[((size_t)widx * 16384) + (size_t)c * 8] = pk;
}

// ---------------- MFMA GEMM: [n,128](bf16) @ W[128,128] ----------------
template <int ACT>
__global__ __launch_bounds__(256) void mgemm_kernel(const unsigned short* __restrict__ in,
                                                    const unsigned short* __restrict__ wtf,
                                                    const float* __restrict__ bias,
                                                    unsigned short* __restrict__ out, int n,
                                                    const float* __restrict__ rw2,
                                                    const float* __restrict__ rb2,
                                                    float* __restrict__ out1) {
  __shared__ unsigned short Alds[8192];   // 16KB: swizzled A tile
  __shared__ unsigned short Wlds[16384];  // 32KB fragment-ordered
  int tid = threadIdx.x;
  int rowBase = blockIdx.x * 64;
  {
    const uint4* src = (const uint4*)wtf;
    uint4* dst = (uint4*)Wlds;
#pragma unroll
    for (int c = 0; c < 8; ++c) dst[c * 256 + tid] = src[c * 256 + tid];
  }
  {
    int k8 = tid & 15, tr = tid >> 4;
#pragma unroll
    for (int c = 0; c < 4; ++c) {
      int row = tr + c * 16;
      int gr = rowBase + row;
      uint4 v = make_uint4(0u, 0u, 0u, 0u);
      if (gr < n) v = *(const uint4*)&in[(size_t)gr * HDIM + k8 * 8];
      int srow = row ^ (k8 & 7);
      *(uint4*)&Alds[k8 * 512 + srow * 8] = v;
    }
  }
  __syncthreads();
  int wv = tid >> 6, lane = tid & 63;
  int l16 = lane >> 4, fcol = lane & 15;
  int lrow = wv * 16 + fcol;
  bf16x8 af[4];
#pragma unroll
  for (int kk = 0; kk < 4; ++kk) {
    int k8 = kk * 4 + l16;
    int srow = lrow ^ (k8 & 7);
    af[kk] = *(const bf16x8*)&Alds[k8 * 512 + srow * 8];
  }
  f32x4 acc[8];
#pragma unroll
  for (int ft = 0; ft < 8; ++ft) acc[ft] = (f32x4)(0.f);
#pragma unroll
  for (int ft = 0; ft < 8; ++ft) {
#pragma unroll
    for (int kk = 0; kk < 4; ++kk) {
      bf16x8 bfr = *(const bf16x8*)&Wlds[(((ft * 4 + kk) * 64) + lane) * 8];
      acc[ft] = __builtin_amdgcn_mfma_f32_16x16x32_bf16(af[kk], bfr, acc[ft], 0, 0, 0);
    }
  }
  int orow0 = rowBase + wv * 16 + l16 * 4;  // D: col=lane&15, row=(lane>>4)*4+reg

  if (ACT == 3) {
    float p[4] = {0.f, 0.f, 0.f, 0.f};
#pragma unroll
    for (int ft = 0; ft < 8; ++ft) {
      int f = ft * 16 + fcol;
      float bb = bias[f], ww = rw2[f];
#pragma unroll
      for (int r = 0; r < 4; ++r) {
        float v = acc[ft][r] + bb;
        v = v > 0.f ? v : 0.01f * v;
        p[r] += v * ww;
      }
    }
#pragma unroll
    for (int d = 1; d < 16; d <<= 1) {
#pragma unroll
      for (int r = 0; r < 4; ++r) p[r] += __shfl_xor(p[r], d, 64);
    }
    if (fcol == 0) {
      float rb = rb2[0];
#pragma unroll
      for (int r = 0; r < 4; ++r) {
        int row = orow0 + r;
        if (row < n) out1[row] = p[r] + rb;
      }
    }
    return;
  }

#pragma unroll
  for (int ft = 0; ft < 8; ++ft) {
    int f = ft * 16 + fcol;
    float bb = (ACT == 2) ? bias[f] : 0.f;
#pragma unroll
    for (int r = 0; r < 4; ++r) {
      int row = orow0 + r;
      if (row < n) {
        float v = acc[ft][r];
        if (ACT == 2) {
          v += bb;
          v = v > 0.f ? v : 0.01f * v;
        }
        out[(size_t)row * HDIM + f] = bf16rn(v);
      }
    }
  }
}

// ---------------- aggregation (pull, CSR): one wave per node, bf16 table ----
__global__ __launch_bounds__(256) void aggregate_kernel(const unsigned short* __restrict__ t,
                                                        const int* __restrict__ off,
                                                        const int2* __restrict__ recs,
                                                        const float* __restrict__ dinv,
                                                        const float* __restrict__ bias,
                                                        unsigned short* __restrict__ out, int n) {
  int node = (blockIdx.x * blockDim.x + threadIdx.x) >> 6;
  int lane = threadIdx.x & 63;
  if (node >= n) return;
  const ushort2* tf = (const ushort2*)t + lane;  // row r at tf[r*64]
  float di = dinv[node];
  float self = di * di;
  ushort2 v = tf[(size_t)node * 64];
  float ax = self * bf16tof(v.x), ay = self * bf16tof(v.y);
  int e0 = off[node], e1 = off[node + 1];
  int e = e0;
  for (; e + 8 <= e1; e += 8) {
    int2 r[8];
    ushort2 u[8];
#pragma unroll
    for (int j = 0; j < 8; ++j) r[j] = recs[e + j];
#pragma unroll
    for (int j = 0; j < 8; ++j) u[j] = tf[(size_t)r[j].x * 64];
#pragma unroll
    for (int j = 0; j < 8; ++j) {
      float w = __int_as_float(r[j].y);
      ax += w * bf16tof(u[j].x);
      ay += w * bf16tof(u[j].y);
    }
  }
  for (; e < e1; ++e) {
    int2 r = recs[e];
    float w = __int_as_float(r.y);
    ushort2 u = tf[(size_t)r.x * 64];
    ax += w * bf16tof(u.x);
    ay += w * bf16tof(u.y);
  }
  const float2* bf = (const float2*)bias + lane;
  float2 b = *bf;
  ax = fmaxf(ax + b.x, 0.f);
  ay = fmaxf(ay + b.y, 0.f);
  ushort2 o;
  o.x = bf16rn(ax);
  o.y = bf16rn(ay);
  *((ushort2*)out + (size_t)node * 64 + lane) = o;
}

// ---------------- host ----------------

static inline size_t align256(size_t x) { return (x + 255) & ~(size_t)255; }

extern "C" void kernel_launch(void* const* d_in, const int* in_sizes, int n_in,
                              void* d_out, int out_size, void* d_ws, size_t ws_size,
                              hipStream_t stream) {
  const float* x   = (const float*)d_in[0];
  const int*   ei  = (const int*)d_in[1];
  const float* W0  = (const float*)d_in[2];
  const float* b0  = (const float*)d_in[3];
  const float* W1  = (const float*)d_in[4];
  const float* b1  = (const float*)d_in[5];
  const float* W2  = (const float*)d_in[6];
  const float* b2  = (const float*)d_in[7];
  const float* Rw0 = (const float*)d_in[8];
  const float* Rb0 = (const float*)d_in[9];
  const float* Rw1 = (const float*)d_in[10];
  const float* Rb1 = (const float*)d_in[11];
  const float* Rw2 = (const float*)d_in[12];
  const float* Rb2 = (const float*)d_in[13];
  float* out = (float*)d_out;

  int N = in_sizes[0] / 6;
  int E = in_sizes[1] / 2;
  int NBK = (N + 63) >> 6;           // 64-node buckets
  int M = NBK * NB1;                 // gh entries
  int MB = (M + 255) / 256;          // chunks for gh-scan
  int chunk = (E + NB1 - 1) / NB1;

  char* p = (char*)d_ws;
  size_t o = 0;
  int* off     = (int*)(p + o); o = align256(o + (size_t)(N + 1) * 4);
  float* dinv  = (float*)(p + o); o = align256(o + (size_t)N * 4);
  int* bsums   = (int*)(p + o); o = align256(o + (size_t)MB * 4);
  int* bscan   = (int*)(p + o); o = align256(o + (size_t)MB * 4);
  int* gh      = (int*)(p + o); o = align256(o + (size_t)M * 4);
  int* ghs     = (int*)(p + o); o = align256(o + (size_t)M * 4);
  int2* tmp    = (int2*)(p + o); o = align256(o + (size_t)E * 8);
  int2* recs   = (int2*)(p + o); o = align256(o + (size_t)E * 8);
  float* aggx  = (float*)(p + o); o = align256(o + (size_t)N * 6 * 4);
  unsigned short* Wtf = (unsigned short*)(p + o); o = align256(o + (size_t)4 * 16384 * 2);
  unsigned short* H0  = (unsigned short*)(p + o); o = align256(o + (size_t)N * HDIM * 2);
  unsigned short* H1  = (unsigned short*)(p + o); o = align256(o + (size_t)N * HDIM * 2);
  (void)ws_size;

  // 2-level counting sort; degrees/off/dinv derived from sorted buckets
  bucket_hist<<<NB1, 1024, 0, stream>>>(ei, E, chunk, gh, NBK);
  chunk_sums_kernel<<<MB, 256, 0, stream>>>(gh, bsums, M);
  small_scan_kernel<<<1, 256, 0, stream>>>(bsums, bscan, MB);
  write_scan_kernel<<<MB, 256, 0, stream>>>(gh, bscan, ghs, M);
  bucket_place<<<NB1, 1024, 0, stream>>>(ei, E, chunk, ghs, tmp, NBK);
  fine_count<<<NBK, 256, 0, stream>>>(tmp, ghs, off, dinv, N, E, NBK);
  fine_sort<<<NBK, 256, 0, stream>>>(tmp, off, ghs, dinv, recs, N, E, NBK);

  // weight prep (independent)
  {
    dim3 g(8, 4);
    wprep_kernel<<<g, 256, 0, stream>>>(W1, W2, Rw0, Rw1, Wtf);
  }

  // layer 0: propagate in 6-dim, then 6->128 gemm + relu -> bf16
  prop6_kernel<<<(N + 31) / 32, 256, 0, stream>>>(x, off, recs, dinv, aggx, N);
  gemm0_kernel<<<(N + 15) / 16, 256, 0, stream>>>(aggx, W0, b0, H0, N);

  int mGrid = (N + 63) / 64;
  int aggGrid = (N + 3) / 4;

  // conv1
  mgemm_kernel<0><<<mGrid, 256, 0, stream>>>(H0, Wtf + 0 * 16384, nullptr, H1, N, nullptr, nullptr, nullptr);
  aggregate_kernel<<<aggGrid, 256, 0, stream>>>(H1, off, recs, dinv, b1, H0, N);
  // conv2
  mgemm_kernel<0><<<mGrid, 256, 0, stream>>>(H0, Wtf + 1 * 16384, nullptr, H1, N, nullptr, nullptr, nullptr);
  aggregate_kernel<<<aggGrid, 256, 0, stream>>>(H1, off, recs, dinv, b2, H0, N);
  // MLP head
  mgemm_kernel<2><<<mGrid, 256, 0, stream>>>(H0, Wtf + 2 * 16384, Rb0, H1, N, nullptr, nullptr, nullptr);
  mgemm_kernel<3><<<mGrid, 256, 0, stream>>>(H1, Wtf + 3 * 16384, Rb1, nullptr, N, Rw2, Rb2, out);
}

// Round 16
// 252.252 us; speedup vs baseline: 1.7029x; 1.0228x over previous
//
#include <hip/hip_runtime.h>

// GCN on MI355X. R16 = R15 with aggregate restructured: 2 nodes/wave,
// 32 lanes/node, ushort4 (4 feats)/lane. One gather instruction fetches TWO
// 256B rows; record loads per half-wave; 2 independent edge streams/wave
// double memory-level parallelism (R15: 60us each, 2.9 TB/s, neither pipe
// saturated). Everything else unchanged from R15 (258us).

#define HDIM 128
#define NB1 128  // sort blocks (level-1)

typedef __attribute__((ext_vector_type(8))) short bf16x8;
typedef __attribute__((ext_vector_type(4))) float f32x4;

__device__ inline unsigned short bf16rn(float f) {
  unsigned u = __float_as_uint(f);
  unsigned r = (u + 0x7FFFu + ((u >> 16) & 1u)) >> 16;
  return (unsigned short)r;
}
__device__ inline float bf16tof(unsigned short h) {
  return __uint_as_float(((unsigned)h) << 16);
}

// ---------------- 3-stage parallel exclusive scan (for gh only) ----------

__global__ __launch_bounds__(256) void chunk_sums_kernel(const int* __restrict__ in,
                                                         int* __restrict__ sums, int M) {
  int i = blockIdx.x * 256 + threadIdx.x;
  int v = (i < M) ? in[i] : 0;
#pragma unroll
  for (int d = 1; d < 64; d <<= 1) v += __shfl_xor(v, d, 64);
  __shared__ int ws[4];
  int lane = threadIdx.x & 63, wid = threadIdx.x >> 6;
  if (lane == 0) ws[wid] = v;
  __syncthreads();
  if (threadIdx.x == 0) sums[blockIdx.x] = ws[0] + ws[1] + ws[2] + ws[3];
}

__global__ __launch_bounds__(256) void small_scan_kernel(const int* __restrict__ in,
                                                         int* __restrict__ outv, int M) {
  __shared__ int wsum[4];
  __shared__ int carry_s;
  int tid = threadIdx.x, lane = tid & 63, wid = tid >> 6;
  if (tid == 0) carry_s = 0;
  __syncthreads();
  int nchunks = (M + 4095) / 4096;
  for (int c = 0; c < nchunks; ++c) {
    int base = c * 4096 + tid * 16;
    int v[16];
#pragma unroll
    for (int j = 0; j < 16; ++j) {
      int i = base + j;
      v[j] = (i < M) ? in[i] : 0;
    }
    int s = 0;
#pragma unroll
    for (int j = 0; j < 16; ++j) { int t = v[j]; v[j] = s; s += t; }
    int tot = s;
    int inc = tot;
#pragma unroll
    for (int d = 1; d < 64; d <<= 1) {
      int t = __shfl_up(inc, (unsigned)d, 64);
      if (lane >= d) inc += t;
    }
    if (lane == 63) wsum[wid] = inc;
    int texcl = inc - tot;
    __syncthreads();
    int wexcl = 0, ctot = 0;
#pragma unroll
    for (int w = 0; w < 4; ++w) {
      int ws = wsum[w];
      if (w < wid) wexcl += ws;
      ctot += ws;
    }
    int cbase = carry_s + wexcl + texcl;
#pragma unroll
    for (int j = 0; j < 16; ++j) {
      int i = base + j;
      if (i < M) outv[i] = cbase + v[j];
    }
    __syncthreads();
    if (tid == 0) carry_s += ctot;
    __syncthreads();
  }
}

__global__ __launch_bounds__(256) void write_scan_kernel(const int* __restrict__ in,
                                                         const int* __restrict__ bases,
                                                         int* __restrict__ outv, int M) {
  int i = blockIdx.x * 256 + threadIdx.x;
  int v = (i < M) ? in[i] : 0;
  int lane = threadIdx.x & 63, wid = threadIdx.x >> 6;
  int inc = v;
#pragma unroll
  for (int d = 1; d < 64; d <<= 1) {
    int t = __shfl_up(inc, (unsigned)d, 64);
    if (lane >= d) inc += t;
  }
  __shared__ int ws[4];
  if (lane == 63) ws[wid] = inc;
  __syncthreads();
  int woff = 0;
  for (int w = 0; w < wid; ++w) woff += ws[w];
  inc += woff;
  int base = bases[blockIdx.x];
  if (i < M) outv[i] = base + inc - v;
}

// ---------------- 2-level counting sort ----------------

__global__ __launch_bounds__(1024) void bucket_hist(const int* __restrict__ ei, int E,
                                                    int chunk, int* __restrict__ gh, int nbk) {
  __shared__ int h[1024];
  int tid = threadIdx.x, b = blockIdx.x;
  for (int i = tid; i < nbk; i += 1024) h[i] = 0;
  __syncthreads();
  int s = b * chunk, e = min(E, s + chunk);
  for (int i = s + tid; i < e; i += 1024) atomicAdd(&h[ei[E + i] >> 6], 1);
  __syncthreads();
  for (int k = tid; k < nbk; k += 1024) gh[k * NB1 + b] = h[k];
}

__global__ __launch_bounds__(1024) void bucket_place(const int* __restrict__ ei, int E,
                                                     int chunk, const int* __restrict__ ghs,
                                                     int2* __restrict__ tmp, int nbk) {
  __shared__ int cur[1024];
  int tid = threadIdx.x, b = blockIdx.x;
  for (int k = tid; k < nbk; k += 1024) cur[k] = ghs[k * NB1 + b];
  __syncthreads();
  int s = b * chunk, e = min(E, s + chunk);
  for (int i = s + tid; i < e; i += 1024) {
    int src = ei[i], dst = ei[E + i];
    int pos = atomicAdd(&cur[dst >> 6], 1);
    tmp[pos] = make_int2(src, dst);
  }
}

__global__ __launch_bounds__(256) void fine_count(const int2* __restrict__ tmp,
                                                  const int* __restrict__ ghs,
                                                  int* __restrict__ off,
                                                  float* __restrict__ dinv,
                                                  int n, int E, int nbk) {
  __shared__ int cnt[64][4];
  int tid = threadIdx.x, k = blockIdx.x;
  ((int*)cnt)[tid] = 0;
  int e0 = ghs[k * NB1];
  int e1 = (k + 1 < nbk) ? ghs[(k + 1) * NB1] : E;
  __syncthreads();
  for (int i = e0 + tid; i < e1; i += 256)
    atomicAdd(&cnt[tmp[i].y & 63][tid & 3], 1);
  __syncthreads();
  if (tid < 64) {
    int c = cnt[tid][0] + cnt[tid][1] + cnt[tid][2] + cnt[tid][3];
    int inc = c;
#pragma unroll
    for (int d = 1; d < 64; d <<= 1) {
      int t = __shfl_up(inc, (unsigned)d, 64);
      if (tid >= d) inc += t;
    }
    int node = k * 64 + tid;
    if (node < n) {
      off[node] = e0 + inc - c;
      dinv[node] = rsqrtf((float)(c + 1));
      if (node == n - 1) off[n] = e0 + inc;
    }
  }
}

__global__ __launch_bounds__(256) void fine_sort(const int2* __restrict__ tmp,
                                                 const int* __restrict__ off,
                                                 const int* __restrict__ ghs,
                                                 const float* __restrict__ dinv,
                                                 int2* __restrict__ recs,
                                                 int n, int E, int nbk) {
  __shared__ int cur[64];
  int tid = threadIdx.x, k = blockIdx.x;
  if (tid < 64) {
    int node = k * 64 + tid;
    cur[tid] = (node < n) ? off[node] : 0;
  }
  int e0 = ghs[k * NB1];
  int e1 = (k + 1 < nbk) ? ghs[(k + 1) * NB1] : E;
  __syncthreads();
  for (int i = e0 + tid; i < e1; i += 256) {
    int2 t = tmp[i];
    int pos = atomicAdd(&cur[t.y & 63], 1);
    float w = dinv[t.x] * dinv[t.y];
    recs[pos] = make_int2(t.x, __float_as_int(w));
  }
}

// ---------------- layer 0: propagate 6-dim features ----------------
__global__ void prop6_kernel(const float* __restrict__ x, const int* __restrict__ off,
                             const int2* __restrict__ recs,
                             const float* __restrict__ dinv, float* __restrict__ aggx, int n) {
  int g = (blockIdx.x * blockDim.x + threadIdx.x) >> 3;
  int l = threadIdx.x & 7;
  if (g >= n) return;
  float di = dinv[g];
  float acc = 0.f;
  if (l < 6) acc = di * di * x[g * 6 + l];
  int e0 = off[g], e1 = off[g + 1];
  int e = e0;
  for (; e + 4 <= e1; e += 4) {
    int2 r0 = recs[e], r1 = recs[e + 1], r2 = recs[e + 2], r3 = recs[e + 3];
    float u0 = 0.f, u1 = 0.f, u2 = 0.f, u3 = 0.f;
    if (l < 6) {
      u0 = x[r0.x * 6 + l]; u1 = x[r1.x * 6 + l];
      u2 = x[r2.x * 6 + l]; u3 = x[r3.x * 6 + l];
    }
    acc += __int_as_float(r0.y) * u0 + __int_as_float(r1.y) * u1 +
           __int_as_float(r2.y) * u2 + __int_as_float(r3.y) * u3;
  }
  for (; e < e1; ++e) {
    int2 r = recs[e];
    if (l < 6) acc += __int_as_float(r.y) * x[r.x * 6 + l];
  }
  if (l < 6) aggx[g * 6 + l] = acc;
}

// h0 = relu(aggx @ W0 + b0): [n,6]x[6,128] -> bf16. 16 nodes per 256-block.
__global__ __launch_bounds__(256) void gemm0_kernel(const float* __restrict__ aggx,
                                                    const float* __restrict__ W0,
                                                    const float* __restrict__ b0,
                                                    unsigned short* __restrict__ out, int n) {
  __shared__ float Ws[6 * 128];
  __shared__ float bs[128];
  for (int i = threadIdx.x; i < 6 * 128; i += 256) Ws[i] = W0[i];
  if (threadIdx.x < 128) bs[threadIdx.x] = b0[threadIdx.x];
  __syncthreads();
  int f = threadIdx.x & 127;
  int h = threadIdx.x >> 7;
  int base = blockIdx.x * 16;
#pragma unroll
  for (int j = 0; j < 8; ++j) {
    int nd = base + h * 8 + j;
    if (nd < n) {
      float acc = bs[f];
#pragma unroll
      for (int k = 0; k < 6; ++k) acc += aggx[nd * 6 + k] * Ws[k * 128 + f];
      out[(size_t)nd * HDIM + f] = bf16rn(fmaxf(acc, 0.f));
    }
  }
}

// ---------------- weight prep: fp32 W[128][128] -> bf16 fragment order -----
__global__ __launch_bounds__(256) void wprep_kernel(const float* __restrict__ w1,
                                                    const float* __restrict__ w2,
                                                    const float* __restrict__ rw0,
                                                    const float* __restrict__ rw1,
                                                    unsigned short* __restrict__ wtf) {
  int widx = blockIdx.y;
  const float* W = (widx == 0) ? w1 : (widx == 1) ? w2 : (widx == 2) ? rw0 : rw1;
  int c = blockIdx.x * 256 + threadIdx.x;  // 0..2047
  int l = c & 63, kk = (c >> 6) & 3, ft = c >> 8;
  int f = ft * 16 + (l & 15);
  int k0 = kk * 32 + ((l >> 4) << 3);
  unsigned short v[8];
#pragma unroll
  for (int j = 0; j < 8; ++j) v[j] = bf16rn(W[(size_t)(k0 + j) * 128 + f]);
  uint4 pk;
  pk.x = (unsigned)v[0] | ((unsigned)v[1] << 16);
  pk.y = (unsigned)v[2] | ((unsigned)v[3] << 16);
  pk.z = (unsigned)v[4] | ((unsigned)v[5] << 16);
  pk.w = (unsigned)v[6] | ((unsigned)v[7] << 16);
  *(uint4*)&wtf[((size_t)widx * 16384) + (size_t)c * 8] = pk;
}

// ---------------- MFMA GEMM: [n,128](bf16) @ W[128,128] ----------------
template <int ACT>
__global__ __launch_bounds__(256) void mgemm_kernel(const unsigned short* __restrict__ in,
                                                    const unsigned short* __restrict__ wtf,
                                                    const float* __restrict__ bias,
                                                    unsigned short* __restrict__ out, int n,
                                                    const float* __restrict__ rw2,
                                                    const float* __restrict__ rb2,
                                                    float* __restrict__ out1) {
  __shared__ unsigned short Alds[8192];   // 16KB: swizzled A tile
  __shared__ unsigned short Wlds[16384];  // 32KB fragment-ordered
  int tid = threadIdx.x;
  int rowBase = blockIdx.x * 64;
  {
    const uint4* src = (const uint4*)wtf;
    uint4* dst = (uint4*)Wlds;
#pragma unroll
    for (int c = 0; c < 8; ++c) dst[c * 256 + tid] = src[c * 256 + tid];
  }
  {
    int k8 = tid & 15, tr = tid >> 4;
#pragma unroll
    for (int c = 0; c < 4; ++c) {
      int row = tr + c * 16;
      int gr = rowBase + row;
      uint4 v = make_uint4(0u, 0u, 0u, 0u);
      if (gr < n) v = *(const uint4*)&in[(size_t)gr * HDIM + k8 * 8];
      int srow = row ^ (k8 & 7);
      *(uint4*)&Alds[k8 * 512 + srow * 8] = v;
    }
  }
  __syncthreads();
  int wv = tid >> 6, lane = tid & 63;
  int l16 = lane >> 4, fcol = lane & 15;
  int lrow = wv * 16 + fcol;
  bf16x8 af[4];
#pragma unroll
  for (int kk = 0; kk < 4; ++kk) {
    int k8 = kk * 4 + l16;
    int srow = lrow ^ (k8 & 7);
    af[kk] = *(const bf16x8*)&Alds[k8 * 512 + srow * 8];
  }
  f32x4 acc[8];
#pragma unroll
  for (int ft = 0; ft < 8; ++ft) acc[ft] = (f32x4)(0.f);
#pragma unroll
  for (int ft = 0; ft < 8; ++ft) {
#pragma unroll
    for (int kk = 0; kk < 4; ++kk) {
      bf16x8 bfr = *(const bf16x8*)&Wlds[(((ft * 4 + kk) * 64) + lane) * 8];
      acc[ft] = __builtin_amdgcn_mfma_f32_16x16x32_bf16(af[kk], bfr, acc[ft], 0, 0, 0);
    }
  }
  int orow0 = rowBase + wv * 16 + l16 * 4;  // D: col=lane&15, row=(lane>>4)*4+reg

  if (ACT == 3) {
    float p[4] = {0.f, 0.f, 0.f, 0.f};
#pragma unroll
    for (int ft = 0; ft < 8; ++ft) {
      int f = ft * 16 + fcol;
      float bb = bias[f], ww = rw2[f];
#pragma unroll
      for (int r = 0; r < 4; ++r) {
        float v = acc[ft][r] + bb;
        v = v > 0.f ? v : 0.01f * v;
        p[r] += v * ww;
      }
    }
#pragma unroll
    for (int d = 1; d < 16; d <<= 1) {
#pragma unroll
      for (int r = 0; r < 4; ++r) p[r] += __shfl_xor(p[r], d, 64);
    }
    if (fcol == 0) {
      float rb = rb2[0];
#pragma unroll
      for (int r = 0; r < 4; ++r) {
        int row = orow0 + r;
        if (row < n) out1[row] = p[r] + rb;
      }
    }
    return;
  }

#pragma unroll
  for (int ft = 0; ft < 8; ++ft) {
    int f = ft * 16 + fcol;
    float bb = (ACT == 2) ? bias[f] : 0.f;
#pragma unroll
    for (int r = 0; r < 4; ++r) {
      int row = orow0 + r;
      if (row < n) {
        float v = acc[ft][r];
        if (ACT == 2) {
          v += bb;
          v = v > 0.f ? v : 0.01f * v;
        }
        out[(size_t)row * HDIM + f] = bf16rn(v);
      }
    }
  }
}

// ---------------- aggregation: 2 nodes/wave, 32 lanes/node, ushort4/lane ----
// One gather instruction fetches two 256B rows (one per half-wave).
__global__ __launch_bounds__(256) void aggregate_kernel(const unsigned short* __restrict__ t,
                                                        const int* __restrict__ off,
                                                        const int2* __restrict__ recs,
                                                        const float* __restrict__ dinv,
                                                        const float* __restrict__ bias,
                                                        unsigned short* __restrict__ out, int n) {
  int wave = (blockIdx.x * blockDim.x + threadIdx.x) >> 6;
  int half = (threadIdx.x >> 5) & 1;
  int lane32 = threadIdx.x & 31;
  int node = wave * 2 + half;
  if (node >= n) return;
  const ushort4* tf = (const ushort4*)t;  // row r feats [lane32*4..+3] at tf[r*32+lane32]
  float di = dinv[node];
  float self = di * di;
  ushort4 v = tf[(size_t)node * 32 + lane32];
  float a0 = self * bf16tof(v.x), a1 = self * bf16tof(v.y);
  float a2 = self * bf16tof(v.z), a3 = self * bf16tof(v.w);
  int e0 = off[node], e1 = off[node + 1];
  int e = e0;
  for (; e + 8 <= e1; e += 8) {
    int2 r[8];
    ushort4 u[8];
#pragma unroll
    for (int j = 0; j < 8; ++j) r[j] = recs[e + j];
#pragma unroll
    for (int j = 0; j < 8; ++j) u[j] = tf[(size_t)r[j].x * 32 + lane32];
#pragma unroll
    for (int j = 0; j < 8; ++j) {
      float w = __int_as_float(r[j].y);
      a0 += w * bf16tof(u[j].x);
      a1 += w * bf16tof(u[j].y);
      a2 += w * bf16tof(u[j].z);
      a3 += w * bf16tof(u[j].w);
    }
  }
  for (; e < e1; ++e) {
    int2 r = recs[e];
    float w = __int_as_float(r.y);
    ushort4 u = tf[(size_t)r.x * 32 + lane32];
    a0 += w * bf16tof(u.x);
    a1 += w * bf16tof(u.y);
    a2 += w * bf16tof(u.z);
    a3 += w * bf16tof(u.w);
  }
  float4 b = *((const float4*)bias + lane32);
  a0 = fmaxf(a0 + b.x, 0.f);
  a1 = fmaxf(a1 + b.y, 0.f);
  a2 = fmaxf(a2 + b.z, 0.f);
  a3 = fmaxf(a3 + b.w, 0.f);
  ushort4 o;
  o.x = bf16rn(a0); o.y = bf16rn(a1); o.z = bf16rn(a2); o.w = bf16rn(a3);
  *((ushort4*)out + (size_t)node * 32 + lane32) = o;
}

// ---------------- host ----------------

static inline size_t align256(size_t x) { return (x + 255) & ~(size_t)255; }

extern "C" void kernel_launch(void* const* d_in, const int* in_sizes, int n_in,
                              void* d_out, int out_size, void* d_ws, size_t ws_size,
                              hipStream_t stream) {
  const float* x   = (const float*)d_in[0];
  const int*   ei  = (const int*)d_in[1];
  const float* W0  = (const float*)d_in[2];
  const float* b0  = (const float*)d_in[3];
  const float* W1  = (const float*)d_in[4];
  const float* b1  = (const float*)d_in[5];
  const float* W2  = (const float*)d_in[6];
  const float* b2  = (const float*)d_in[7];
  const float* Rw0 = (const float*)d_in[8];
  const float* Rb0 = (const float*)d_in[9];
  const float* Rw1 = (const float*)d_in[10];
  const float* Rb1 = (const float*)d_in[11];
  const float* Rw2 = (const float*)d_in[12];
  const float* Rb2 = (const float*)d_in[13];
  float* out = (float*)d_out;

  int N = in_sizes[0] / 6;
  int E = in_sizes[1] / 2;
  int NBK = (N + 63) >> 6;           // 64-node buckets
  int M = NBK * NB1;                 // gh entries
  int MB = (M + 255) / 256;          // chunks for gh-scan
  int chunk = (E + NB1 - 1) / NB1;

  char* p = (char*)d_ws;
  size_t o = 0;
  int* off     = (int*)(p + o); o = align256(o + (size_t)(N + 1) * 4);
  float* dinv  = (float*)(p + o); o = align256(o + (size_t)N * 4);
  int* bsums   = (int*)(p + o); o = align256(o + (size_t)MB * 4);
  int* bscan   = (int*)(p + o); o = align256(o + (size_t)MB * 4);
  int* gh      = (int*)(p + o); o = align256(o + (size_t)M * 4);
  int* ghs     = (int*)(p + o); o = align256(o + (size_t)M * 4);
  int2* tmp    = (int2*)(p + o); o = align256(o + (size_t)E * 8);
  int2* recs   = (int2*)(p + o); o = align256(o + (size_t)E * 8);
  float* aggx  = (float*)(p + o); o = align256(o + (size_t)N * 6 * 4);
  unsigned short* Wtf = (unsigned short*)(p + o); o = align256(o + (size_t)4 * 16384 * 2);
  unsigned short* H0  = (unsigned short*)(p + o); o = align256(o + (size_t)N * HDIM * 2);
  unsigned short* H1  = (unsigned short*)(p + o); o = align256(o + (size_t)N * HDIM * 2);
  (void)ws_size;

  // 2-level counting sort; degrees/off/dinv derived from sorted buckets
  bucket_hist<<<NB1, 1024, 0, stream>>>(ei, E, chunk, gh, NBK);
  chunk_sums_kernel<<<MB, 256, 0, stream>>>(gh, bsums, M);
  small_scan_kernel<<<1, 256, 0, stream>>>(bsums, bscan, MB);
  write_scan_kernel<<<MB, 256, 0, stream>>>(gh, bscan, ghs, M);
  bucket_place<<<NB1, 1024, 0, stream>>>(ei, E, chunk, ghs, tmp, NBK);
  fine_count<<<NBK, 256, 0, stream>>>(tmp, ghs, off, dinv, N, E, NBK);
  fine_sort<<<NBK, 256, 0, stream>>>(tmp, off, ghs, dinv, recs, N, E, NBK);

  // weight prep (independent)
  {
    dim3 g(8, 4);
    wprep_kernel<<<g, 256, 0, stream>>>(W1, W2, Rw0, Rw1, Wtf);
  }

  // layer 0: propagate in 6-dim, then 6->128 gemm + relu -> bf16
  prop6_kernel<<<(N + 31) / 32, 256, 0, stream>>>(x, off, recs, dinv, aggx, N);
  gemm0_kernel<<<(N + 15) / 16, 256, 0, stream>>>(aggx, W0, b0, H0, N);

  int mGrid = (N + 63) / 64;
  int aggGrid = (N + 7) / 8;  // 2 nodes/wave * 4 waves/block

  // conv1
  mgemm_kernel<0><<<mGrid, 256, 0, stream>>>(H0, Wtf + 0 * 16384, nullptr, H1, N, nullptr, nullptr, nullptr);
  aggregate_kernel<<<aggGrid, 256, 0, stream>>>(H1, off, recs, dinv, b1, H0, N);
  // conv2
  mgemm_kernel<0><<<mGrid, 256, 0, stream>>>(H0, Wtf + 1 * 16384, nullptr, H1, N, nullptr, nullptr, nullptr);
  aggregate_kernel<<<aggGrid, 256, 0, stream>>>(H1, off, recs, dinv, b2, H0, N);
  // MLP head
  mgemm_kernel<2><<<mGrid, 256, 0, stream>>>(H0, Wtf + 2 * 16384, Rb0, H1, N, nullptr, nullptr, nullptr);
  mgemm_kernel<3><<<mGrid, 256, 0, stream>>>(H1, Wtf + 3 * 16384, Rb1, nullptr, N, Rw2, Rb2, out);
}

// Round 17
// 194.748 us; speedup vs baseline: 2.2057x; 1.2953x over previous
//
#include <hip/hip_runtime.h>

// GCN on MI355X. R17:
//  - conv message tables in fp8 e4m3 (table 12.8->6.4MB; aggregate was pinned
//    at the L2-miss ceiling ~2.8TB/s x 157MB). HW cvt_pk fp8<->f32.
//  - MLP head fused: (A@Rw0+b0->leaky)@Rw1+b1->leaky . Rw2 + rb2 in ONE
//    kernel (80KB LDS), removing a 25.6MB round trip + a dispatch.
// Rest identical to R16 (252us).

#define HDIM 128
#define NB1 128  // sort blocks (level-1)

typedef __attribute__((ext_vector_type(8))) short bf16x8;
typedef __attribute__((ext_vector_type(4))) float f32x4;
typedef __attribute__((ext_vector_type(2))) float f32x2;

__device__ inline unsigned short bf16rn(float f) {
  unsigned u = __float_as_uint(f);
  unsigned r = (u + 0x7FFFu + ((u >> 16) & 1u)) >> 16;
  return (unsigned short)r;
}
__device__ inline float bf16tof(unsigned short h) {
  return __uint_as_float(((unsigned)h) << 16);
}
__device__ inline unsigned char fp8enc(float f) {
  return (unsigned char)(__builtin_amdgcn_cvt_pk_fp8_f32(f, f, 0, false) & 0xFF);
}

// ---------------- 3-stage parallel exclusive scan (for gh only) ----------

__global__ __launch_bounds__(256) void chunk_sums_kernel(const int* __restrict__ in,
                                                         int* __restrict__ sums, int M) {
  int i = blockIdx.x * 256 + threadIdx.x;
  int v = (i < M) ? in[i] : 0;
#pragma unroll
  for (int d = 1; d < 64; d <<= 1) v += __shfl_xor(v, d, 64);
  __shared__ int ws[4];
  int lane = threadIdx.x & 63, wid = threadIdx.x >> 6;
  if (lane == 0) ws[wid] = v;
  __syncthreads();
  if (threadIdx.x == 0) sums[blockIdx.x] = ws[0] + ws[1] + ws[2] + ws[3];
}

__global__ __launch_bounds__(256) void small_scan_kernel(const int* __restrict__ in,
                                                         int* __restrict__ outv, int M) {
  __shared__ int wsum[4];
  __shared__ int carry_s;
  int tid = threadIdx.x, lane = tid & 63, wid = tid >> 6;
  if (tid == 0) carry_s = 0;
  __syncthreads();
  int nchunks = (M + 4095) / 4096;
  for (int c = 0; c < nchunks; ++c) {
    int base = c * 4096 + tid * 16;
    int v[16];
#pragma unroll
    for (int j = 0; j < 16; ++j) {
      int i = base + j;
      v[j] = (i < M) ? in[i] : 0;
    }
    int s = 0;
#pragma unroll
    for (int j = 0; j < 16; ++j) { int t = v[j]; v[j] = s; s += t; }
    int tot = s;
    int inc = tot;
#pragma unroll
    for (int d = 1; d < 64; d <<= 1) {
      int t = __shfl_up(inc, (unsigned)d, 64);
      if (lane >= d) inc += t;
    }
    if (lane == 63) wsum[wid] = inc;
    int texcl = inc - tot;
    __syncthreads();
    int wexcl = 0, ctot = 0;
#pragma unroll
    for (int w = 0; w < 4; ++w) {
      int ws = wsum[w];
      if (w < wid) wexcl += ws;
      ctot += ws;
    }
    int cbase = carry_s + wexcl + texcl;
#pragma unroll
    for (int j = 0; j < 16; ++j) {
      int i = base + j;
      if (i < M) outv[i] = cbase + v[j];
    }
    __syncthreads();
    if (tid == 0) carry_s += ctot;
    __syncthreads();
  }
}

__global__ __launch_bounds__(256) void write_scan_kernel(const int* __restrict__ in,
                                                         const int* __restrict__ bases,
                                                         int* __restrict__ outv, int M) {
  int i = blockIdx.x * 256 + threadIdx.x;
  int v = (i < M) ? in[i] : 0;
  int lane = threadIdx.x & 63, wid = threadIdx.x >> 6;
  int inc = v;
#pragma unroll
  for (int d = 1; d < 64; d <<= 1) {
    int t = __shfl_up(inc, (unsigned)d, 64);
    if (lane >= d) inc += t;
  }
  __shared__ int ws[4];
  if (lane == 63) ws[wid] = inc;
  __syncthreads();
  int woff = 0;
  for (int w = 0; w < wid; ++w) woff += ws[w];
  inc += woff;
  int base = bases[blockIdx.x];
  if (i < M) outv[i] = base + inc - v;
}

// ---------------- 2-level counting sort ----------------

__global__ __launch_bounds__(1024) void bucket_hist(const int* __restrict__ ei, int E,
                                                    int chunk, int* __restrict__ gh, int nbk) {
  __shared__ int h[1024];
  int tid = threadIdx.x, b = blockIdx.x;
  for (int i = tid; i < nbk; i += 1024) h[i] = 0;
  __syncthreads();
  int s = b * chunk, e = min(E, s + chunk);
  for (int i = s + tid; i < e; i += 1024) atomicAdd(&h[ei[E + i] >> 6], 1);
  __syncthreads();
  for (int k = tid; k < nbk; k += 1024) gh[k * NB1 + b] = h[k];
}

__global__ __launch_bounds__(1024) void bucket_place(const int* __restrict__ ei, int E,
                                                     int chunk, const int* __restrict__ ghs,
                                                     int2* __restrict__ tmp, int nbk) {
  __shared__ int cur[1024];
  int tid = threadIdx.x, b = blockIdx.x;
  for (int k = tid; k < nbk; k += 1024) cur[k] = ghs[k * NB1 + b];
  __syncthreads();
  int s = b * chunk, e = min(E, s + chunk);
  for (int i = s + tid; i < e; i += 1024) {
    int src = ei[i], dst = ei[E + i];
    int pos = atomicAdd(&cur[dst >> 6], 1);
    tmp[pos] = make_int2(src, dst);
  }
}

__global__ __launch_bounds__(256) void fine_count(const int2* __restrict__ tmp,
                                                  const int* __restrict__ ghs,
                                                  int* __restrict__ off,
                                                  float* __restrict__ dinv,
                                                  int n, int E, int nbk) {
  __shared__ int cnt[64][4];
  int tid = threadIdx.x, k = blockIdx.x;
  ((int*)cnt)[tid] = 0;
  int e0 = ghs[k * NB1];
  int e1 = (k + 1 < nbk) ? ghs[(k + 1) * NB1] : E;
  __syncthreads();
  for (int i = e0 + tid; i < e1; i += 256)
    atomicAdd(&cnt[tmp[i].y & 63][tid & 3], 1);
  __syncthreads();
  if (tid < 64) {
    int c = cnt[tid][0] + cnt[tid][1] + cnt[tid][2] + cnt[tid][3];
    int inc = c;
#pragma unroll
    for (int d = 1; d < 64; d <<= 1) {
      int t = __shfl_up(inc, (unsigned)d, 64);
      if (tid >= d) inc += t;
    }
    int node = k * 64 + tid;
    if (node < n) {
      off[node] = e0 + inc - c;
      dinv[node] = rsqrtf((float)(c + 1));
      if (node == n - 1) off[n] = e0 + inc;
    }
  }
}

__global__ __launch_bounds__(256) void fine_sort(const int2* __restrict__ tmp,
                                                 const int* __restrict__ off,
                                                 const int* __restrict__ ghs,
                                                 const float* __restrict__ dinv,
                                                 int2* __restrict__ recs,
                                                 int n, int E, int nbk) {
  __shared__ int cur[64];
  int tid = threadIdx.x, k = blockIdx.x;
  if (tid < 64) {
    int node = k * 64 + tid;
    cur[tid] = (node < n) ? off[node] : 0;
  }
  int e0 = ghs[k * NB1];
  int e1 = (k + 1 < nbk) ? ghs[(k + 1) * NB1] : E;
  __syncthreads();
  for (int i = e0 + tid; i < e1; i += 256) {
    int2 t = tmp[i];
    int pos = atomicAdd(&cur[t.y & 63], 1);
    float w = dinv[t.x] * dinv[t.y];
    recs[pos] = make_int2(t.x, __float_as_int(w));
  }
}

// ---------------- layer 0: propagate 6-dim features ----------------
__global__ void prop6_kernel(const float* __restrict__ x, const int* __restrict__ off,
                             const int2* __restrict__ recs,
                             const float* __restrict__ dinv, float* __restrict__ aggx, int n) {
  int g = (blockIdx.x * blockDim.x + threadIdx.x) >> 3;
  int l = threadIdx.x & 7;
  if (g >= n) return;
  float di = dinv[g];
  float acc = 0.f;
  if (l < 6) acc = di * di * x[g * 6 + l];
  int e0 = off[g], e1 = off[g + 1];
  int e = e0;
  for (; e + 4 <= e1; e += 4) {
    int2 r0 = recs[e], r1 = recs[e + 1], r2 = recs[e + 2], r3 = recs[e + 3];
    float u0 = 0.f, u1 = 0.f, u2 = 0.f, u3 = 0.f;
    if (l < 6) {
      u0 = x[r0.x * 6 + l]; u1 = x[r1.x * 6 + l];
      u2 = x[r2.x * 6 + l]; u3 = x[r3.x * 6 + l];
    }
    acc += __int_as_float(r0.y) * u0 + __int_as_float(r1.y) * u1 +
           __int_as_float(r2.y) * u2 + __int_as_float(r3.y) * u3;
  }
  for (; e < e1; ++e) {
    int2 r = recs[e];
    if (l < 6) acc += __int_as_float(r.y) * x[r.x * 6 + l];
  }
  if (l < 6) aggx[g * 6 + l] = acc;
}

// h0 = relu(aggx @ W0 + b0): [n,6]x[6,128] -> bf16. 16 nodes per 256-block.
__global__ __launch_bounds__(256) void gemm0_kernel(const float* __restrict__ aggx,
                                                    const float* __restrict__ W0,
                                                    const float* __restrict__ b0,
                                                    unsigned short* __restrict__ out, int n) {
  __shared__ float Ws[6 * 128];
  __shared__ float bs[128];
  for (int i = threadIdx.x; i < 6 * 128; i += 256) Ws[i] = W0[i];
  if (threadIdx.x < 128) bs[threadIdx.x] = b0[threadIdx.x];
  __syncthreads();
  int f = threadIdx.x & 127;
  int h = threadIdx.x >> 7;
  int base = blockIdx.x * 16;
#pragma unroll
  for (int j = 0; j < 8; ++j) {
    int nd = base + h * 8 + j;
    if (nd < n) {
      float acc = bs[f];
#pragma unroll
      for (int k = 0; k < 6; ++k) acc += aggx[nd * 6 + k] * Ws[k * 128 + f];
      out[(size_t)nd * HDIM + f] = bf16rn(fmaxf(acc, 0.f));
    }
  }
}

// ---------------- weight prep: fp32 W[128][128] -> bf16 fragment order -----
__global__ __launch_bounds__(256) void wprep_kernel(const float* __restrict__ w1,
                                                    const float* __restrict__ w2,
                                                    const float* __restrict__ rw0,
                                                    const float* __restrict__ rw1,
                                                    unsigned short* __restrict__ wtf) {
  int widx = blockIdx.y;
  const float* W = (widx == 0) ? w1 : (widx == 1) ? w2 : (widx == 2) ? rw0 : rw1;
  int c = blockIdx.x * 256 + threadIdx.x;  // 0..2047
  int l = c & 63, kk = (c >> 6) & 3, ft = c >> 8;
  int f = ft * 16 + (l & 15);
  int k0 = kk * 32 + ((l >> 4) << 3);
  unsigned short v[8];
#pragma unroll
  for (int j = 0; j < 8; ++j) v[j] = bf16rn(W[(size_t)(k0 + j) * 128 + f]);
  uint4 pk;
  pk.x = (unsigned)v[0] | ((unsigned)v[1] << 16);
  pk.y = (unsigned)v[2] | ((unsigned)v[3] << 16);
  pk.z = (unsigned)v[4] | ((unsigned)v[5] << 16);
  pk.w = (unsigned)v[6] | ((unsigned)v[7] << 16);
  *(uint4*)&wtf[((size_t)widx * 16384) + (size_t)c * 8] = pk;
}

// ---------------- MFMA GEMM (conv transform): bf16 in -> fp8 table out -----
__global__ __launch_bounds__(256) void mgemm_kernel(const unsigned short* __restrict__ in,
                                                    const unsigned short* __restrict__ wtf,
                                                    unsigned char* __restrict__ out8, int n) {
  __shared__ unsigned short Alds[8192];   // 16KB: swizzled A tile
  __shared__ unsigned short Wlds[16384];  // 32KB fragment-ordered
  int tid = threadIdx.x;
  int rowBase = blockIdx.x * 64;
  {
    const uint4* src = (const uint4*)wtf;
    uint4* dst = (uint4*)Wlds;
#pragma unroll
    for (int c = 0; c < 8; ++c) dst[c * 256 + tid] = src[c * 256 + tid];
  }
  {
    int k8 = tid & 15, tr = tid >> 4;
#pragma unroll
    for (int c = 0; c < 4; ++c) {
      int row = tr + c * 16;
      int gr = rowBase + row;
      uint4 v = make_uint4(0u, 0u, 0u, 0u);
      if (gr < n) v = *(const uint4*)&in[(size_t)gr * HDIM + k8 * 8];
      int srow = row ^ (k8 & 7);
      *(uint4*)&Alds[k8 * 512 + srow * 8] = v;
    }
  }
  __syncthreads();
  int wv = tid >> 6, lane = tid & 63;
  int l16 = lane >> 4, fcol = lane & 15;
  int lrow = wv * 16 + fcol;
  bf16x8 af[4];
#pragma unroll
  for (int kk = 0; kk < 4; ++kk) {
    int k8 = kk * 4 + l16;
    int srow = lrow ^ (k8 & 7);
    af[kk] = *(const bf16x8*)&Alds[k8 * 512 + srow * 8];
  }
  f32x4 acc[8];
#pragma unroll
  for (int ft = 0; ft < 8; ++ft) acc[ft] = (f32x4)(0.f);
#pragma unroll
  for (int ft = 0; ft < 8; ++ft) {
#pragma unroll
    for (int kk = 0; kk < 4; ++kk) {
      bf16x8 bfr = *(const bf16x8*)&Wlds[(((ft * 4 + kk) * 64) + lane) * 8];
      acc[ft] = __builtin_amdgcn_mfma_f32_16x16x32_bf16(af[kk], bfr, acc[ft], 0, 0, 0);
    }
  }
  int orow0 = rowBase + wv * 16 + l16 * 4;  // D: col=lane&15, row=(lane>>4)*4+reg
#pragma unroll
  for (int ft = 0; ft < 8; ++ft) {
    int f = ft * 16 + fcol;
#pragma unroll
    for (int r = 0; r < 4; ++r) {
      int row = orow0 + r;
      if (row < n) out8[(size_t)row * HDIM + f] = fp8enc(acc[ft][r]);
    }
  }
}

// ---------------- fused MLP head: leaky(leaky(A@Rw0+b0)@Rw1+b1).Rw2 + rb2 --
__global__ __launch_bounds__(256) void mgemm_head(const unsigned short* __restrict__ in,
                                                  const unsigned short* __restrict__ wtf0,
                                                  const unsigned short* __restrict__ wtf1,
                                                  const float* __restrict__ b0,
                                                  const float* __restrict__ b1,
                                                  const float* __restrict__ rw2,
                                                  const float* __restrict__ rb2,
                                                  float* __restrict__ out1, int n) {
  __shared__ unsigned short Wlds0[16384];  // 32KB
  __shared__ unsigned short Wlds1[16384];  // 32KB
  __shared__ unsigned short Alds[8192];    // 16KB (A tile, then B tile)
  int tid = threadIdx.x;
  int rowBase = blockIdx.x * 64;
  {
    const uint4* s0 = (const uint4*)wtf0;
    const uint4* s1 = (const uint4*)wtf1;
    uint4* d0 = (uint4*)Wlds0;
    uint4* d1 = (uint4*)Wlds1;
#pragma unroll
    for (int c = 0; c < 8; ++c) {
      d0[c * 256 + tid] = s0[c * 256 + tid];
      d1[c * 256 + tid] = s1[c * 256 + tid];
    }
  }
  {
    int k8 = tid & 15, tr = tid >> 4;
#pragma unroll
    for (int c = 0; c < 4; ++c) {
      int row = tr + c * 16;
      int gr = rowBase + row;
      uint4 v = make_uint4(0u, 0u, 0u, 0u);
      if (gr < n) v = *(const uint4*)&in[(size_t)gr * HDIM + k8 * 8];
      int srow = row ^ (k8 & 7);
      *(uint4*)&Alds[k8 * 512 + srow * 8] = v;
    }
  }
  __syncthreads();
  int wv = tid >> 6, lane = tid & 63;
  int l16 = lane >> 4, fcol = lane & 15;
  int lrow = wv * 16 + fcol;
  bf16x8 af[4];
#pragma unroll
  for (int kk = 0; kk < 4; ++kk) {
    int k8 = kk * 4 + l16;
    int srow = lrow ^ (k8 & 7);
    af[kk] = *(const bf16x8*)&Alds[k8 * 512 + srow * 8];
  }
  __syncthreads();  // all A reads done before B overwrites Alds
  f32x4 acc[8];
#pragma unroll
  for (int ft = 0; ft < 8; ++ft) acc[ft] = (f32x4)(0.f);
#pragma unroll
  for (int ft = 0; ft < 8; ++ft) {
#pragma unroll
    for (int kk = 0; kk < 4; ++kk) {
      bf16x8 bfr = *(const bf16x8*)&Wlds0[(((ft * 4 + kk) * 64) + lane) * 8];
      acc[ft] = __builtin_amdgcn_mfma_f32_16x16x32_bf16(af[kk], bfr, acc[ft], 0, 0, 0);
    }
  }
  // B = leaky(acc + b0) -> write bf16 into Alds (same swizzled layout)
  int brow0 = wv * 16 + l16 * 4;  // block-local rows
#pragma unroll
  for (int ft = 0; ft < 8; ++ft) {
    int f = ft * 16 + fcol;
    float bb = b0[f];
    int k8 = f >> 3, elem = f & 7;
#pragma unroll
    for (int r = 0; r < 4; ++r) {
      float v = acc[ft][r] + bb;
      v = v > 0.f ? v : 0.01f * v;
      int row = brow0 + r;
      int srow = row ^ (k8 & 7);
      Alds[k8 * 512 + srow * 8 + elem] = bf16rn(v);
    }
  }
  __syncthreads();
  bf16x8 bf2[4];
#pragma unroll
  for (int kk = 0; kk < 4; ++kk) {
    int k8 = kk * 4 + l16;
    int srow = lrow ^ (k8 & 7);
    bf2[kk] = *(const bf16x8*)&Alds[k8 * 512 + srow * 8];
  }
  f32x4 acc2[8];
#pragma unroll
  for (int ft = 0; ft < 8; ++ft) acc2[ft] = (f32x4)(0.f);
#pragma unroll
  for (int ft = 0; ft < 8; ++ft) {
#pragma unroll
    for (int kk = 0; kk < 4; ++kk) {
      bf16x8 bfr = *(const bf16x8*)&Wlds1[(((ft * 4 + kk) * 64) + lane) * 8];
      acc2[ft] = __builtin_amdgcn_mfma_f32_16x16x32_bf16(bf2[kk], bfr, acc2[ft], 0, 0, 0);
    }
  }
  int orow0 = rowBase + wv * 16 + l16 * 4;
  float p[4] = {0.f, 0.f, 0.f, 0.f};
#pragma unroll
  for (int ft = 0; ft < 8; ++ft) {
    int f = ft * 16 + fcol;
    float bb = b1[f], ww = rw2[f];
#pragma unroll
    for (int r = 0; r < 4; ++r) {
      float v = acc2[ft][r] + bb;
      v = v > 0.f ? v : 0.01f * v;
      p[r] += v * ww;
    }
  }
#pragma unroll
  for (int d = 1; d < 16; d <<= 1) {
#pragma unroll
    for (int r = 0; r < 4; ++r) p[r] += __shfl_xor(p[r], d, 64);
  }
  if (fcol == 0) {
    float rb = rb2[0];
#pragma unroll
    for (int r = 0; r < 4; ++r) {
      int row = orow0 + r;
      if (row < n) out1[row] = p[r] + rb;
    }
  }
}

// ---------------- aggregation: fp8 table, 2 nodes/wave, 32 lanes/node -------
__global__ __launch_bounds__(256) void aggregate_kernel(const unsigned char* __restrict__ t8,
                                                        const int* __restrict__ off,
                                                        const int2* __restrict__ recs,
                                                        const float* __restrict__ dinv,
                                                        const float* __restrict__ bias,
                                                        unsigned short* __restrict__ out, int n) {
  int wave = (blockIdx.x * blockDim.x + threadIdx.x) >> 6;
  int half = (threadIdx.x >> 5) & 1;
  int lane32 = threadIdx.x & 31;
  int node = wave * 2 + half;
  if (node >= n) return;
  const unsigned* tf = (const unsigned*)t8;  // row r feats [lane32*4..+3] at tf[r*32+lane32]
  float di = dinv[node];
  float self = di * di;
  unsigned v = tf[(size_t)node * 32 + lane32];
  f32x2 vlo = __builtin_amdgcn_cvt_pk_f32_fp8(v, false);
  f32x2 vhi = __builtin_amdgcn_cvt_pk_f32_fp8(v, true);
  float a0 = self * vlo[0], a1 = self * vlo[1];
  float a2 = self * vhi[0], a3 = self * vhi[1];
  int e0 = off[node], e1 = off[node + 1];
  int e = e0;
  for (; e + 8 <= e1; e += 8) {
    int2 r[8];
    unsigned u[8];
#pragma unroll
    for (int j = 0; j < 8; ++j) r[j] = recs[e + j];
#pragma unroll
    for (int j = 0; j < 8; ++j) u[j] = tf[(size_t)r[j].x * 32 + lane32];
#pragma unroll
    for (int j = 0; j < 8; ++j) {
      float w = __int_as_float(r[j].y);
      f32x2 lo = __builtin_amdgcn_cvt_pk_f32_fp8(u[j], false);
      f32x2 hi = __builtin_amdgcn_cvt_pk_f32_fp8(u[j], true);
      a0 += w * lo[0]; a1 += w * lo[1];
      a2 += w * hi[0]; a3 += w * hi[1];
    }
  }
  for (; e < e1; ++e) {
    int2 r = recs[e];
    float w = __int_as_float(r.y);
    unsigned u = tf[(size_t)r.x * 32 + lane32];
    f32x2 lo = __builtin_amdgcn_cvt_pk_f32_fp8(u, false);
    f32x2 hi = __builtin_amdgcn_cvt_pk_f32_fp8(u, true);
    a0 += w * lo[0]; a1 += w * lo[1];
    a2 += w * hi[0]; a3 += w * hi[1];
  }
  float4 b = *((const float4*)bias + lane32);
  a0 = fmaxf(a0 + b.x, 0.f);
  a1 = fmaxf(a1 + b.y, 0.f);
  a2 = fmaxf(a2 + b.z, 0.f);
  a3 = fmaxf(a3 + b.w, 0.f);
  ushort4 o;
  o.x = bf16rn(a0); o.y = bf16rn(a1); o.z = bf16rn(a2); o.w = bf16rn(a3);
  *((ushort4*)out + (size_t)node * 32 + lane32) = o;
}

// ---------------- host ----------------

static inline size_t align256(size_t x) { return (x + 255) & ~(size_t)255; }

extern "C" void kernel_launch(void* const* d_in, const int* in_sizes, int n_in,
                              void* d_out, int out_size, void* d_ws, size_t ws_size,
                              hipStream_t stream) {
  const float* x   = (const float*)d_in[0];
  const int*   ei  = (const int*)d_in[1];
  const float* W0  = (const float*)d_in[2];
  const float* b0  = (const float*)d_in[3];
  const float* W1  = (const float*)d_in[4];
  const float* b1  = (const float*)d_in[5];
  const float* W2  = (const float*)d_in[6];
  const float* b2  = (const float*)d_in[7];
  const float* Rw0 = (const float*)d_in[8];
  const float* Rb0 = (const float*)d_in[9];
  const float* Rw1 = (const float*)d_in[10];
  const float* Rb1 = (const float*)d_in[11];
  const float* Rw2 = (const float*)d_in[12];
  const float* Rb2 = (const float*)d_in[13];
  float* out = (float*)d_out;

  int N = in_sizes[0] / 6;
  int E = in_sizes[1] / 2;
  int NBK = (N + 63) >> 6;           // 64-node buckets
  int M = NBK * NB1;                 // gh entries
  int MB = (M + 255) / 256;          // chunks for gh-scan
  int chunk = (E + NB1 - 1) / NB1;

  char* p = (char*)d_ws;
  size_t o = 0;
  int* off     = (int*)(p + o); o = align256(o + (size_t)(N + 1) * 4);
  float* dinv  = (float*)(p + o); o = align256(o + (size_t)N * 4);
  int* bsums   = (int*)(p + o); o = align256(o + (size_t)MB * 4);
  int* bscan   = (int*)(p + o); o = align256(o + (size_t)MB * 4);
  int* gh      = (int*)(p + o); o = align256(o + (size_t)M * 4);
  int* ghs     = (int*)(p + o); o = align256(o + (size_t)M * 4);
  int2* tmp    = (int2*)(p + o); o = align256(o + (size_t)E * 8);
  int2* recs   = (int2*)(p + o); o = align256(o + (size_t)E * 8);
  float* aggx  = (float*)(p + o); o = align256(o + (size_t)N * 6 * 4);
  unsigned short* Wtf = (unsigned short*)(p + o); o = align256(o + (size_t)4 * 16384 * 2);
  unsigned short* H0  = (unsigned short*)(p + o); o = align256(o + (size_t)N * HDIM * 2);
  unsigned char*  H1  = (unsigned char*)(p + o); o = align256(o + (size_t)N * HDIM);
  (void)ws_size;

  // 2-level counting sort; degrees/off/dinv derived from sorted buckets
  bucket_hist<<<NB1, 1024, 0, stream>>>(ei, E, chunk, gh, NBK);
  chunk_sums_kernel<<<MB, 256, 0, stream>>>(gh, bsums, M);
  small_scan_kernel<<<1, 256, 0, stream>>>(bsums, bscan, MB);
  write_scan_kernel<<<MB, 256, 0, stream>>>(gh, bscan, ghs, M);
  bucket_place<<<NB1, 1024, 0, stream>>>(ei, E, chunk, ghs, tmp, NBK);
  fine_count<<<NBK, 256, 0, stream>>>(tmp, ghs, off, dinv, N, E, NBK);
  fine_sort<<<NBK, 256, 0, stream>>>(tmp, off, ghs, dinv, recs, N, E, NBK);

  // weight prep (independent)
  {
    dim3 g(8, 4);
    wprep_kernel<<<g, 256, 0, stream>>>(W1, W2, Rw0, Rw1, Wtf);
  }

  // layer 0: propagate in 6-dim, then 6->128 gemm + relu -> bf16
  prop6_kernel<<<(N + 31) / 32, 256, 0, stream>>>(x, off, recs, dinv, aggx, N);
  gemm0_kernel<<<(N + 15) / 16, 256, 0, stream>>>(aggx, W0, b0, H0, N);

  int mGrid = (N + 63) / 64;
  int aggGrid = (N + 7) / 8;  // 2 nodes/wave * 4 waves/block

  // conv1: transform -> fp8 table -> aggregate -> bf16 H0
  mgemm_kernel<<<mGrid, 256, 0, stream>>>(H0, Wtf + 0 * 16384, H1, N);
  aggregate_kernel<<<aggGrid, 256, 0, stream>>>(H1, off, recs, dinv, b1, H0, N);
  // conv2
  mgemm_kernel<<<mGrid, 256, 0, stream>>>(H0, Wtf + 1 * 16384, H1, N);
  aggregate_kernel<<<aggGrid, 256, 0, stream>>>(H1, off, recs, dinv, b2, H0, N);
  // fused MLP head
  mgemm_head<<<mGrid, 256, 0, stream>>>(H0, Wtf + 2 * 16384, Wtf + 3 * 16384,
                                        Rb0, Rb1, Rw2, Rb2, out, N);
}

// Round 18
// 190.696 us; speedup vs baseline: 2.2526x; 1.0213x over previous
//
#include <hip/hip_runtime.h>

// GCN on MI355X. R18:
//  - fine_count+fine_sort fused into fine_build (bucket edges staged in LDS
//    once; count -> wave scan (off,dinv) -> place). Saves a 12.8MB tmp pass.
//  - dinv[s] folded into tables: t' = dinv*(h@W) (mgemm epilogue), xp=dinv*x.
//    recs shrink 8B -> 4B (src only); aggregate: relu(dinv[d]*(Sum+self)+b).
// R17 = 194.7us, fp8 tables, absmax 4.9e-4.

#define HDIM 128
#define NB1 128   // sort blocks (level-1)
#define SCAP 4096 // fine_build LDS stage capacity (edges)

typedef __attribute__((ext_vector_type(8))) short bf16x8;
typedef __attribute__((ext_vector_type(4))) float f32x4;
typedef __attribute__((ext_vector_type(2))) float f32x2;

__device__ inline unsigned short bf16rn(float f) {
  unsigned u = __float_as_uint(f);
  unsigned r = (u + 0x7FFFu + ((u >> 16) & 1u)) >> 16;
  return (unsigned short)r;
}
__device__ inline float bf16tof(unsigned short h) {
  return __uint_as_float(((unsigned)h) << 16);
}
__device__ inline unsigned char fp8enc(float f) {
  return (unsigned char)(__builtin_amdgcn_cvt_pk_fp8_f32(f, f, 0, false) & 0xFF);
}

// ---------------- 3-stage parallel exclusive scan (for gh) ----------------

__global__ __launch_bounds__(256) void chunk_sums_kernel(const int* __restrict__ in,
                                                         int* __restrict__ sums, int M) {
  int i = blockIdx.x * 256 + threadIdx.x;
  int v = (i < M) ? in[i] : 0;
#pragma unroll
  for (int d = 1; d < 64; d <<= 1) v += __shfl_xor(v, d, 64);
  __shared__ int ws[4];
  int lane = threadIdx.x & 63, wid = threadIdx.x >> 6;
  if (lane == 0) ws[wid] = v;
  __syncthreads();
  if (threadIdx.x == 0) sums[blockIdx.x] = ws[0] + ws[1] + ws[2] + ws[3];
}

__global__ __launch_bounds__(256) void small_scan_kernel(const int* __restrict__ in,
                                                         int* __restrict__ outv, int M) {
  __shared__ int wsum[4];
  __shared__ int carry_s;
  int tid = threadIdx.x, lane = tid & 63, wid = tid >> 6;
  if (tid == 0) carry_s = 0;
  __syncthreads();
  int nchunks = (M + 4095) / 4096;
  for (int c = 0; c < nchunks; ++c) {
    int base = c * 4096 + tid * 16;
    int v[16];
#pragma unroll
    for (int j = 0; j < 16; ++j) {
      int i = base + j;
      v[j] = (i < M) ? in[i] : 0;
    }
    int s = 0;
#pragma unroll
    for (int j = 0; j < 16; ++j) { int t = v[j]; v[j] = s; s += t; }
    int tot = s;
    int inc = tot;
#pragma unroll
    for (int d = 1; d < 64; d <<= 1) {
      int t = __shfl_up(inc, (unsigned)d, 64);
      if (lane >= d) inc += t;
    }
    if (lane == 63) wsum[wid] = inc;
    int texcl = inc - tot;
    __syncthreads();
    int wexcl = 0, ctot = 0;
#pragma unroll
    for (int w = 0; w < 4; ++w) {
      int ws = wsum[w];
      if (w < wid) wexcl += ws;
      ctot += ws;
    }
    int cbase = carry_s + wexcl + texcl;
#pragma unroll
    for (int j = 0; j < 16; ++j) {
      int i = base + j;
      if (i < M) outv[i] = cbase + v[j];
    }
    __syncthreads();
    if (tid == 0) carry_s += ctot;
    __syncthreads();
  }
}

__global__ __launch_bounds__(256) void write_scan_kernel(const int* __restrict__ in,
                                                         const int* __restrict__ bases,
                                                         int* __restrict__ outv, int M) {
  int i = blockIdx.x * 256 + threadIdx.x;
  int v = (i < M) ? in[i] : 0;
  int lane = threadIdx.x & 63, wid = threadIdx.x >> 6;
  int inc = v;
#pragma unroll
  for (int d = 1; d < 64; d <<= 1) {
    int t = __shfl_up(inc, (unsigned)d, 64);
    if (lane >= d) inc += t;
  }
  __shared__ int ws[4];
  if (lane == 63) ws[wid] = inc;
  __syncthreads();
  int woff = 0;
  for (int w = 0; w < wid; ++w) woff += ws[w];
  inc += woff;
  int base = bases[blockIdx.x];
  if (i < M) outv[i] = base + inc - v;
}

// ---------------- 2-level counting sort ----------------

__global__ __launch_bounds__(1024) void bucket_hist(const int* __restrict__ ei, int E,
                                                    int chunk, int* __restrict__ gh, int nbk) {
  __shared__ int h[1024];
  int tid = threadIdx.x, b = blockIdx.x;
  for (int i = tid; i < nbk; i += 1024) h[i] = 0;
  __syncthreads();
  int s = b * chunk, e = min(E, s + chunk);
  for (int i = s + tid; i < e; i += 1024) atomicAdd(&h[ei[E + i] >> 6], 1);
  __syncthreads();
  for (int k = tid; k < nbk; k += 1024) gh[k * NB1 + b] = h[k];
}

__global__ __launch_bounds__(1024) void bucket_place(const int* __restrict__ ei, int E,
                                                     int chunk, const int* __restrict__ ghs,
                                                     int2* __restrict__ tmp, int nbk) {
  __shared__ int cur[1024];
  int tid = threadIdx.x, b = blockIdx.x;
  for (int k = tid; k < nbk; k += 1024) cur[k] = ghs[k * NB1 + b];
  __syncthreads();
  int s = b * chunk, e = min(E, s + chunk);
  for (int i = s + tid; i < e; i += 1024) {
    int src = ei[i], dst = ei[E + i];
    int pos = atomicAdd(&cur[dst >> 6], 1);
    tmp[pos] = make_int2(src, dst);
  }
}

// fused: stage bucket edges in LDS -> count (4-copy) -> wave scan (off,dinv)
// -> place src-only records. One 12.8MB tmp pass instead of two.
__global__ __launch_bounds__(256) void fine_build(const int2* __restrict__ tmp,
                                                  const int* __restrict__ ghs,
                                                  int* __restrict__ off,
                                                  float* __restrict__ dinv,
                                                  int* __restrict__ recs,
                                                  int n, int E, int nbk) {
  __shared__ int2 stage[SCAP];  // 32KB
  __shared__ int cnt[64][4];    // 1KB
  __shared__ int cur[64];
  int tid = threadIdx.x, k = blockIdx.x;
  ((int*)cnt)[tid & 255] = 0;
  int e0 = ghs[k * NB1];
  int e1 = (k + 1 < nbk) ? ghs[(k + 1) * NB1] : E;
  int cntE = e1 - e0;
  int nst = cntE < SCAP ? cntE : SCAP;
  __syncthreads();
  // stage + count
  for (int i = tid; i < nst; i += 256) {
    int2 t = tmp[e0 + i];
    stage[i] = t;
    atomicAdd(&cnt[t.y & 63][tid & 3], 1);
  }
  for (int i = nst + tid; i < cntE; i += 256)  // overflow (rare)
    atomicAdd(&cnt[tmp[e0 + i].y & 63][tid & 3], 1);
  __syncthreads();
  if (tid < 64) {
    int c = cnt[tid][0] + cnt[tid][1] + cnt[tid][2] + cnt[tid][3];
    int inc = c;
#pragma unroll
    for (int d = 1; d < 64; d <<= 1) {
      int t = __shfl_up(inc, (unsigned)d, 64);
      if (tid >= d) inc += t;
    }
    int node = k * 64 + tid;
    if (node < n) {
      off[node] = e0 + inc - c;
      cur[tid] = e0 + inc - c;
      dinv[node] = rsqrtf((float)(c + 1));
      if (node == n - 1) off[n] = e0 + inc;
    } else {
      cur[tid] = 0;
    }
  }
  __syncthreads();
  // place
  for (int i = tid; i < nst; i += 256) {
    int2 t = stage[i];
    int pos = atomicAdd(&cur[t.y & 63], 1);
    recs[pos] = t.x;
  }
  for (int i = nst + tid; i < cntE; i += 256) {
    int2 t = tmp[e0 + i];
    int pos = atomicAdd(&cur[t.y & 63], 1);
    recs[pos] = t.x;
  }
}

// ---------------- layer 0 ----------------

// xp = dinv[node] * x
__global__ void xprescale_kernel(const float* __restrict__ x, const float* __restrict__ dinv,
                                 float* __restrict__ xp, int n) {
  int i = blockIdx.x * blockDim.x + threadIdx.x;
  if (i < n * 6) xp[i] = x[i] * dinv[i / 6];
}

// aggx[d] = dinv[d] * (sum xp[src] + xp[d])  (6-dim, src-only recs)
__global__ void prop6_kernel(const float* __restrict__ xp, const int* __restrict__ off,
                             const int* __restrict__ recs,
                             const float* __restrict__ dinv, float* __restrict__ aggx, int n) {
  int g = (blockIdx.x * blockDim.x + threadIdx.x) >> 3;
  int l = threadIdx.x & 7;
  if (g >= n) return;
  float acc = 0.f;
  if (l < 6) acc = xp[g * 6 + l];
  int e0 = off[g], e1 = off[g + 1];
  int e = e0;
  for (; e + 4 <= e1; e += 4) {
    int s0 = recs[e], s1 = recs[e + 1], s2 = recs[e + 2], s3 = recs[e + 3];
    if (l < 6)
      acc += xp[s0 * 6 + l] + xp[s1 * 6 + l] + xp[s2 * 6 + l] + xp[s3 * 6 + l];
  }
  for (; e < e1; ++e) {
    int s = recs[e];
    if (l < 6) acc += xp[s * 6 + l];
  }
  if (l < 6) aggx[g * 6 + l] = dinv[g] * acc;
}

// h0 = relu(aggx @ W0 + b0) -> bf16. 16 nodes per 256-block.
__global__ __launch_bounds__(256) void gemm0_kernel(const float* __restrict__ aggx,
                                                    const float* __restrict__ W0,
                                                    const float* __restrict__ b0,
                                                    unsigned short* __restrict__ out, int n) {
  __shared__ float Ws[6 * 128];
  __shared__ float bs[128];
  for (int i = threadIdx.x; i < 6 * 128; i += 256) Ws[i] = W0[i];
  if (threadIdx.x < 128) bs[threadIdx.x] = b0[threadIdx.x];
  __syncthreads();
  int f = threadIdx.x & 127;
  int h = threadIdx.x >> 7;
  int base = blockIdx.x * 16;
#pragma unroll
  for (int j = 0; j < 8; ++j) {
    int nd = base + h * 8 + j;
    if (nd < n) {
      float acc = bs[f];
#pragma unroll
      for (int k = 0; k < 6; ++k) acc += aggx[nd * 6 + k] * Ws[k * 128 + f];
      out[(size_t)nd * HDIM + f] = bf16rn(fmaxf(acc, 0.f));
    }
  }
}

// ---------------- weight prep: fp32 W[128][128] -> bf16 fragment order -----
__global__ __launch_bounds__(256) void wprep_kernel(const float* __restrict__ w1,
                                                    const float* __restrict__ w2,
                                                    const float* __restrict__ rw0,
                                                    const float* __restrict__ rw1,
                                                    unsigned short* __restrict__ wtf) {
  int widx = blockIdx.y;
  const float* W = (widx == 0) ? w1 : (widx == 1) ? w2 : (widx == 2) ? rw0 : rw1;
  int c = blockIdx.x * 256 + threadIdx.x;  // 0..2047
  int l = c & 63, kk = (c >> 6) & 3, ft = c >> 8;
  int f = ft * 16 + (l & 15);
  int k0 = kk * 32 + ((l >> 4) << 3);
  unsigned short v[8];
#pragma unroll
  for (int j = 0; j < 8; ++j) v[j] = bf16rn(W[(size_t)(k0 + j) * 128 + f]);
  uint4 pk;
  pk.x = (unsigned)v[0] | ((unsigned)v[1] << 16);
  pk.y = (unsigned)v[2] | ((unsigned)v[3] << 16);
  pk.z = (unsigned)v[4] | ((unsigned)v[5] << 16);
  pk.w = (unsigned)v[6] | ((unsigned)v[7] << 16);
  *(uint4*)&wtf[((size_t)widx * 16384) + (size_t)c * 8] = pk;
}

// ---------------- MFMA GEMM (conv transform): t' = dinv*(h@W) -> fp8 -------
__global__ __launch_bounds__(256) void mgemm_kernel(const unsigned short* __restrict__ in,
                                                    const unsigned short* __restrict__ wtf,
                                                    const float* __restrict__ dinv,
                                                    unsigned char* __restrict__ out8, int n) {
  __shared__ unsigned short Alds[8192];   // 16KB swizzled A tile
  __shared__ unsigned short Wlds[16384];  // 32KB fragment-ordered
  int tid = threadIdx.x;
  int rowBase = blockIdx.x * 64;
  {
    const uint4* src = (const uint4*)wtf;
    uint4* dst = (uint4*)Wlds;
#pragma unroll
    for (int c = 0; c < 8; ++c) dst[c * 256 + tid] = src[c * 256 + tid];
  }
  {
    int k8 = tid & 15, tr = tid >> 4;
#pragma unroll
    for (int c = 0; c < 4; ++c) {
      int row = tr + c * 16;
      int gr = rowBase + row;
      uint4 v = make_uint4(0u, 0u, 0u, 0u);
      if (gr < n) v = *(const uint4*)&in[(size_t)gr * HDIM + k8 * 8];
      int srow = row ^ (k8 & 7);
      *(uint4*)&Alds[k8 * 512 + srow * 8] = v;
    }
  }
  __syncthreads();
  int wv = tid >> 6, lane = tid & 63;
  int l16 = lane >> 4, fcol = lane & 15;
  int lrow = wv * 16 + fcol;
  bf16x8 af[4];
#pragma unroll
  for (int kk = 0; kk < 4; ++kk) {
    int k8 = kk * 4 + l16;
    int srow = lrow ^ (k8 & 7);
    af[kk] = *(const bf16x8*)&Alds[k8 * 512 + srow * 8];
  }
  f32x4 acc[8];
#pragma unroll
  for (int ft = 0; ft < 8; ++ft) acc[ft] = (f32x4)(0.f);
#pragma unroll
  for (int ft = 0; ft < 8; ++ft) {
#pragma unroll
    for (int kk = 0; kk < 4; ++kk) {
      bf16x8 bfr = *(const bf16x8*)&Wlds[(((ft * 4 + kk) * 64) + lane) * 8];
      acc[ft] = __builtin_amdgcn_mfma_f32_16x16x32_bf16(af[kk], bfr, acc[ft], 0, 0, 0);
    }
  }
  int orow0 = rowBase + wv * 16 + l16 * 4;  // D: col=lane&15, row=(lane>>4)*4+reg
  float dv[4];
#pragma unroll
  for (int r = 0; r < 4; ++r) {
    int row = orow0 + r;
    dv[r] = (row < n) ? dinv[row] : 0.f;
  }
#pragma unroll
  for (int ft = 0; ft < 8; ++ft) {
    int f = ft * 16 + fcol;
#pragma unroll
    for (int r = 0; r < 4; ++r) {
      int row = orow0 + r;
      if (row < n) out8[(size_t)row * HDIM + f] = fp8enc(dv[r] * acc[ft][r]);
    }
  }
}

// ---------------- fused MLP head ----------------
__global__ __launch_bounds__(256) void mgemm_head(const unsigned short* __restrict__ in,
                                                  const unsigned short* __restrict__ wtf0,
                                                  const unsigned short* __restrict__ wtf1,
                                                  const float* __restrict__ b0,
                                                  const float* __restrict__ b1,
                                                  const float* __restrict__ rw2,
                                                  const float* __restrict__ rb2,
                                                  float* __restrict__ out1, int n) {
  __shared__ unsigned short Wlds0[16384];
  __shared__ unsigned short Wlds1[16384];
  __shared__ unsigned short Alds[8192];
  int tid = threadIdx.x;
  int rowBase = blockIdx.x * 64;
  {
    const uint4* s0 = (const uint4*)wtf0;
    const uint4* s1 = (const uint4*)wtf1;
    uint4* d0 = (uint4*)Wlds0;
    uint4* d1 = (uint4*)Wlds1;
#pragma unroll
    for (int c = 0; c < 8; ++c) {
      d0[c * 256 + tid] = s0[c * 256 + tid];
      d1[c * 256 + tid] = s1[c * 256 + tid];
    }
  }
  {
    int k8 = tid & 15, tr = tid >> 4;
#pragma unroll
    for (int c = 0; c < 4; ++c) {
      int row = tr + c * 16;
      int gr = rowBase + row;
      uint4 v = make_uint4(0u, 0u, 0u, 0u);
      if (gr < n) v = *(const uint4*)&in[(size_t)gr * HDIM + k8 * 8];
      int srow = row ^ (k8 & 7);
      *(uint4*)&Alds[k8 * 512 + srow * 8] = v;
    }
  }
  __syncthreads();
  int wv = tid >> 6, lane = tid & 63;
  int l16 = lane >> 4, fcol = lane & 15;
  int lrow = wv * 16 + fcol;
  bf16x8 af[4];
#pragma unroll
  for (int kk = 0; kk < 4; ++kk) {
    int k8 = kk * 4 + l16;
    int srow = lrow ^ (k8 & 7);
    af[kk] = *(const bf16x8*)&Alds[k8 * 512 + srow * 8];
  }
  __syncthreads();
  f32x4 acc[8];
#pragma unroll
  for (int ft = 0; ft < 8; ++ft) acc[ft] = (f32x4)(0.f);
#pragma unroll
  for (int ft = 0; ft < 8; ++ft) {
#pragma unroll
    for (int kk = 0; kk < 4; ++kk) {
      bf16x8 bfr = *(const bf16x8*)&Wlds0[(((ft * 4 + kk) * 64) + lane) * 8];
      acc[ft] = __builtin_amdgcn_mfma_f32_16x16x32_bf16(af[kk], bfr, acc[ft], 0, 0, 0);
    }
  }
  int brow0 = wv * 16 + l16 * 4;
#pragma unroll
  for (int ft = 0; ft < 8; ++ft) {
    int f = ft * 16 + fcol;
    float bb = b0[f];
    int k8 = f >> 3, elem = f & 7;
#pragma unroll
    for (int r = 0; r < 4; ++r) {
      float v = acc[ft][r] + bb;
      v = v > 0.f ? v : 0.01f * v;
      int row = brow0 + r;
      int srow = row ^ (k8 & 7);
      Alds[k8 * 512 + srow * 8 + elem] = bf16rn(v);
    }
  }
  __syncthreads();
  bf16x8 bf2[4];
#pragma unroll
  for (int kk = 0; kk < 4; ++kk) {
    int k8 = kk * 4 + l16;
    int srow = lrow ^ (k8 & 7);
    bf2[kk] = *(const bf16x8*)&Alds[k8 * 512 + srow * 8];
  }
  f32x4 acc2[8];
#pragma unroll
  for (int ft = 0; ft < 8; ++ft) acc2[ft] = (f32x4)(0.f);
#pragma unroll
  for (int ft = 0; ft < 8; ++ft) {
#pragma unroll
    for (int kk = 0; kk < 4; ++kk) {
      bf16x8 bfr = *(const bf16x8*)&Wlds1[(((ft * 4 + kk) * 64) + lane) * 8];
      acc2[ft] = __builtin_amdgcn_mfma_f32_16x16x32_bf16(bf2[kk], bfr, acc2[ft], 0, 0, 0);
    }
  }
  int orow0 = rowBase + wv * 16 + l16 * 4;
  float p[4] = {0.f, 0.f, 0.f, 0.f};
#pragma unroll
  for (int ft = 0; ft < 8; ++ft) {
    int f = ft * 16 + fcol;
    float bb = b1[f], ww = rw2[f];
#pragma unroll
    for (int r = 0; r < 4; ++r) {
      float v = acc2[ft][r] + bb;
      v = v > 0.f ? v : 0.01f * v;
      p[r] += v * ww;
    }
  }
#pragma unroll
  for (int d = 1; d < 16; d <<= 1) {
#pragma unroll
    for (int r = 0; r < 4; ++r) p[r] += __shfl_xor(p[r], d, 64);
  }
  if (fcol == 0) {
    float rb = rb2[0];
#pragma unroll
    for (int r = 0; r < 4; ++r) {
      int row = orow0 + r;
      if (row < n) out1[row] = p[r] + rb;
    }
  }
}

// ---------------- aggregation: prescaled fp8 table, src-only recs ----------
// out[d] = relu(dinv[d]*(sum t'[src] + t'[d]) + b); 2 nodes/wave, 32 l/node.
__global__ __launch_bounds__(256) void aggregate_kernel(const unsigned char* __restrict__ t8,
                                                        const int* __restrict__ off,
                                                        const int* __restrict__ recs,
                                                        const float* __restrict__ dinv,
                                                        const float* __restrict__ bias,
                                                        unsigned short* __restrict__ out, int n) {
  int wave = (blockIdx.x * blockDim.x + threadIdx.x) >> 6;
  int half = (threadIdx.x >> 5) & 1;
  int lane32 = threadIdx.x & 31;
  int node = wave * 2 + half;
  if (node >= n) return;
  const unsigned* tf = (const unsigned*)t8;  // row r feats [lane32*4..+3]
  unsigned v = tf[(size_t)node * 32 + lane32];
  f32x2 vlo = __builtin_amdgcn_cvt_pk_f32_fp8(v, false);
  f32x2 vhi = __builtin_amdgcn_cvt_pk_f32_fp8(v, true);
  float a0 = vlo[0], a1 = vlo[1], a2 = vhi[0], a3 = vhi[1];
  int e0 = off[node], e1 = off[node + 1];
  int e = e0;
  for (; e + 8 <= e1; e += 8) {
    int s[8];
    unsigned u[8];
#pragma unroll
    for (int j = 0; j < 8; ++j) s[j] = recs[e + j];
#pragma unroll
    for (int j = 0; j < 8; ++j) u[j] = tf[(size_t)s[j] * 32 + lane32];
#pragma unroll
    for (int j = 0; j < 8; ++j) {
      f32x2 lo = __builtin_amdgcn_cvt_pk_f32_fp8(u[j], false);
      f32x2 hi = __builtin_amdgcn_cvt_pk_f32_fp8(u[j], true);
      a0 += lo[0]; a1 += lo[1]; a2 += hi[0]; a3 += hi[1];
    }
  }
  for (; e < e1; ++e) {
    unsigned u = tf[(size_t)recs[e] * 32 + lane32];
    f32x2 lo = __builtin_amdgcn_cvt_pk_f32_fp8(u, false);
    f32x2 hi = __builtin_amdgcn_cvt_pk_f32_fp8(u, true);
    a0 += lo[0]; a1 += lo[1]; a2 += hi[0]; a3 += hi[1];
  }
  float di = dinv[node];
  float4 b = *((const float4*)bias + lane32);
  a0 = fmaxf(di * a0 + b.x, 0.f);
  a1 = fmaxf(di * a1 + b.y, 0.f);
  a2 = fmaxf(di * a2 + b.z, 0.f);
  a3 = fmaxf(di * a3 + b.w, 0.f);
  ushort4 o;
  o.x = bf16rn(a0); o.y = bf16rn(a1); o.z = bf16rn(a2); o.w = bf16rn(a3);
  *((ushort4*)out + (size_t)node * 32 + lane32) = o;
}

// ---------------- host ----------------

static inline size_t align256(size_t x) { return (x + 255) & ~(size_t)255; }

extern "C" void kernel_launch(void* const* d_in, const int* in_sizes, int n_in,
                              void* d_out, int out_size, void* d_ws, size_t ws_size,
                              hipStream_t stream) {
  const float* x   = (const float*)d_in[0];
  const int*   ei  = (const int*)d_in[1];
  const float* W0  = (const float*)d_in[2];
  const float* b0  = (const float*)d_in[3];
  const float* W1  = (const float*)d_in[4];
  const float* b1  = (const float*)d_in[5];
  const float* W2  = (const float*)d_in[6];
  const float* b2  = (const float*)d_in[7];
  const float* Rw0 = (const float*)d_in[8];
  const float* Rb0 = (const float*)d_in[9];
  const float* Rw1 = (const float*)d_in[10];
  const float* Rb1 = (const float*)d_in[11];
  const float* Rw2 = (const float*)d_in[12];
  const float* Rb2 = (const float*)d_in[13];
  float* out = (float*)d_out;

  int N = in_sizes[0] / 6;
  int E = in_sizes[1] / 2;
  int NBK = (N + 63) >> 6;           // 64-node buckets
  int M = NBK * NB1;                 // gh entries
  int MB = (M + 255) / 256;          // chunks for gh-scan
  int chunk = (E + NB1 - 1) / NB1;

  char* p = (char*)d_ws;
  size_t o = 0;
  int* off     = (int*)(p + o); o = align256(o + (size_t)(N + 1) * 4);
  float* dinv  = (float*)(p + o); o = align256(o + (size_t)N * 4);
  int* bsums   = (int*)(p + o); o = align256(o + (size_t)MB * 4);
  int* bscan   = (int*)(p + o); o = align256(o + (size_t)MB * 4);
  int* gh      = (int*)(p + o); o = align256(o + (size_t)M * 4);
  int* ghs     = (int*)(p + o); o = align256(o + (size_t)M * 4);
  int2* tmp    = (int2*)(p + o); o = align256(o + (size_t)E * 8);
  int* recs    = (int*)(p + o); o = align256(o + (size_t)E * 4);
  float* xp    = (float*)(p + o); o = align256(o + (size_t)N * 6 * 4);
  float* aggx  = (float*)(p + o); o = align256(o + (size_t)N * 6 * 4);
  unsigned short* Wtf = (unsigned short*)(p + o); o = align256(o + (size_t)4 * 16384 * 2);
  unsigned short* H0  = (unsigned short*)(p + o); o = align256(o + (size_t)N * HDIM * 2);
  unsigned char*  H1  = (unsigned char*)(p + o); o = align256(o + (size_t)N * HDIM);
  (void)ws_size;

  // 2-level counting sort; off/dinv/recs built from sorted buckets
  bucket_hist<<<NB1, 1024, 0, stream>>>(ei, E, chunk, gh, NBK);
  chunk_sums_kernel<<<MB, 256, 0, stream>>>(gh, bsums, M);
  small_scan_kernel<<<1, 256, 0, stream>>>(bsums, bscan, MB);
  write_scan_kernel<<<MB, 256, 0, stream>>>(gh, bscan, ghs, M);
  bucket_place<<<NB1, 1024, 0, stream>>>(ei, E, chunk, ghs, tmp, NBK);
  fine_build<<<NBK, 256, 0, stream>>>(tmp, ghs, off, dinv, recs, N, E, NBK);

  // weight prep (independent)
  {
    dim3 g(8, 4);
    wprep_kernel<<<g, 256, 0, stream>>>(W1, W2, Rw0, Rw1, Wtf);
  }

  // layer 0: prescale -> propagate (6-dim) -> gemm0 -> bf16 H0
  xprescale_kernel<<<(N * 6 + 255) / 256, 256, 0, stream>>>(x, dinv, xp, N);
  prop6_kernel<<<(N + 31) / 32, 256, 0, stream>>>(xp, off, recs, dinv, aggx, N);
  gemm0_kernel<<<(N + 15) / 16, 256, 0, stream>>>(aggx, W0, b0, H0, N);

  int mGrid = (N + 63) / 64;
  int aggGrid = (N + 7) / 8;

  // conv1: transform (prescaled fp8 table) -> aggregate -> bf16 H0
  mgemm_kernel<<<mGrid, 256, 0, stream>>>(H0, Wtf + 0 * 16384, dinv, H1, N);
  aggregate_kernel<<<aggGrid, 256, 0, stream>>>(H1, off, recs, dinv, b1, H0, N);
  // conv2
  mgemm_kernel<<<mGrid, 256, 0, stream>>>(H0, Wtf + 1 * 16384, dinv, H1, N);
  aggregate_kernel<<<aggGrid, 256, 0, stream>>>(H1, off, recs, dinv, b2, H0, N);
  // fused MLP head
  mgemm_head<<<mGrid, 256, 0, stream>>>(H0, Wtf + 2 * 16384, Wtf + 3 * 16384,
                                        Rb0, Rb1, Rw2, Rb2, out, N);
}